// Round 1
// baseline (92776.959 us; speedup 1.0000x reference)
//
#include <hip/hip_runtime.h>
#include <math.h>

// Problem sizes (fixed)
#define VSZ 32000
#define Hh  768
#define Cc  256
#define HCd 1024
#define G4  4096
#define LL  2048
#define NSE 2046   // encoder steps
#define NSD 2047   // decoder steps

// Persistent-scan launch shape: 128 blocks x 512 threads (8 waves) -> 1024 waves,
// one wave per output element j in [0,1024). Guaranteed co-resident (<=256 CUs).
#define PB 128
#define PT 512

__device__ __forceinline__ float sigmoidf_(float x){ return 1.0f/(1.0f+expf(-x)); }

__device__ __forceinline__ float wave_reduce(float v){
#pragma unroll
  for(int o=32;o;o>>=1) v += __shfl_xor(v,o,64);
  return v;
}

// Monotonic-counter grid barrier (all PB blocks co-resident).
__device__ __forceinline__ void gbar(unsigned* ctr, unsigned target){
  __threadfence();            // make prior global writes device-visible
  __syncthreads();            // drains vmcnt for all waves in block
  if(threadIdx.x==0){
    __hip_atomic_fetch_add(ctr,1u,__ATOMIC_RELEASE,__HIP_MEMORY_SCOPE_AGENT);
    while(__hip_atomic_load(ctr,__ATOMIC_ACQUIRE,__HIP_MEMORY_SCOPE_AGENT) < target){
      __builtin_amdgcn_s_sleep(1);
    }
  }
  __syncthreads();
}

__global__ void k_init(unsigned* ctrs){
  if(threadIdx.x<4) ctrs[threadIdx.x]=0u;
}

// dec_const[r] = dec_W_hh[r,0:768]·fc_h_b + dec_W_hh[r,768:1024]·cd
__global__ __launch_bounds__(256) void k_dconst(const float* __restrict__ Whh,
    const float* __restrict__ fhb, const float* __restrict__ cemb,
    const int* __restrict__ condp, float* __restrict__ cvec){
  int lane=threadIdx.x&63, wv=threadIdx.x>>6;
  int wgid=blockIdx.x*4+wv;            // 256 waves
  int cond=condp[0];
  for(int r=wgid;r<G4;r+=256){
    const float* row=Whh+(size_t)r*HCd;
    float s=0.f;
    for(int k=lane;k<Hh;k+=64) s+=row[k]*fhb[k];
    for(int k=lane;k<Cc;k+=64) s+=row[Hh+k]*cemb[cond*Cc+k];
    s=wave_reduce(s);
    if(lane==0) cvec[r]=s;
  }
}

// Weff[r,k] = sum_{i<768} dec_W_hh[r,i]*fc_h_w[i,k]   (M=4096,N=1024,K=768)
#define GBM 128
#define GBN 128
#define GBK 16
__global__ __launch_bounds__(256) void k_weff(const float* __restrict__ A,
    const float* __restrict__ B, float* __restrict__ Cm){
  __shared__ float As[GBK][GBM];
  __shared__ float Bs[GBK][GBN];
  int tid=threadIdx.x;
  int m0=blockIdx.x*GBM, n0=blockIdx.y*GBN;
  int tm=tid>>4, tn=tid&15;
  float acc[8][8]={};
  for(int k0=0;k0<Hh;k0+=GBK){
#pragma unroll
    for(int u=0;u<2;u++){
      int idx=tid*2+u;
      int row=idx>>2, q=idx&3;                      // A: 128 rows x 4 float4
      float4 v=*(const float4*)(A+(size_t)(m0+row)*HCd + k0+q*4);
      As[q*4+0][row]=v.x; As[q*4+1][row]=v.y; As[q*4+2][row]=v.z; As[q*4+3][row]=v.w;
      int kk=idx>>5, nc=idx&31;                     // B: 16 rows x 32 float4
      float4 w=*(const float4*)(B+(size_t)(k0+kk)*HCd + n0+nc*4);
      *(float4*)&Bs[kk][nc*4]=w;
    }
    __syncthreads();
#pragma unroll
    for(int kk=0;kk<GBK;kk++){
      float a[8],b[8];
      *(float4*)&a[0]=*(float4*)&As[kk][tm*8]; *(float4*)&a[4]=*(float4*)&As[kk][tm*8+4];
      *(float4*)&b[0]=*(float4*)&Bs[kk][tn*8]; *(float4*)&b[4]=*(float4*)&Bs[kk][tn*8+4];
#pragma unroll
      for(int i=0;i<8;i++)
#pragma unroll
        for(int j=0;j<8;j++) acc[i][j]+=a[i]*b[j];
    }
    __syncthreads();
  }
#pragma unroll
  for(int i=0;i<8;i++)
#pragma unroll
    for(int j=0;j<8;j++)
      Cm[(size_t)(m0+tm*8+i)*HCd + n0+tn*8+j]=acc[i][j];
}

// ---------------- Encoder persistent scan ----------------
__global__ __launch_bounds__(PT,2) void k_encoder(
    const int* __restrict__ tok, const int* __restrict__ condp,
    const float* __restrict__ emb, const float* __restrict__ cemb,
    const float* __restrict__ Wih, const float* __restrict__ Whh,
    const float* __restrict__ bih, const float* __restrict__ bhh,
    float* hbuf, float* hT, float* cT, unsigned* ctr)
{
  __shared__ float hlds[HCd];
  __shared__ int   tlds[LL];
  const int tid=threadIdx.x, lane=tid&63, wv=tid>>6;
  const int j=blockIdx.x*8+wv;           // owned output element
  const int cond=condp[0];
  for(int i=tid;i<LL;i+=PT) tlds[i]=tok[i];
  for(int i=tid;i<HCd;i+=PT) hlds[i]=(i<Hh)?0.f:cemb[cond*Cc+(i-Hh)];
  __syncthreads();

  float wih[4][16], whh[4][16], bias[4];
#pragma unroll
  for(int q=0;q<4;q++){
    const float* pw=Wih+(size_t)(q*HCd+j)*HCd+lane*16;
    const float* ph=Whh+(size_t)(q*HCd+j)*HCd+lane*16;
#pragma unroll
    for(int e=0;e<16;e+=4){
      *(float4*)&wih[q][e]=*(const float4*)(pw+e);
      *(float4*)&whh[q][e]=*(const float4*)(ph+e);
    }
    bias[q]=bih[q*HCd+j]+bhh[q*HCd+j];
  }
  float c=(j<Hh)?0.f:cemb[cond*Cc+(j-Hh)];

  float x[16];
  { const float* px=emb+(size_t)tlds[1]*HCd+lane*16;
#pragma unroll
    for(int e=0;e<16;e+=4) *(float4*)&x[e]=*(const float4*)(px+e); }

  for(int t=0;t<NSE;t++){
    float a0=0,a1=0,a2=0,a3=0;
#pragma unroll
    for(int e=0;e<16;e++){ float xv=x[e];
      a0+=wih[0][e]*xv; a1+=wih[1][e]*xv; a2+=wih[2][e]*xv; a3+=wih[3][e]*xv; }
    if(t+1<NSE){                               // prefetch next embedding row
      const float* px=emb+(size_t)tlds[t+2]*HCd+lane*16;
#pragma unroll
      for(int e=0;e<16;e+=4) *(float4*)&x[e]=*(const float4*)(px+e);
    }
    float hseg[16];
#pragma unroll
    for(int e=0;e<16;e+=4) *(float4*)&hseg[e]=*(float4*)&hlds[lane*16+e];
#pragma unroll
    for(int e=0;e<16;e++){ float hv=hseg[e];
      a0+=whh[0][e]*hv; a1+=whh[1][e]*hv; a2+=whh[2][e]*hv; a3+=whh[3][e]*hv; }
    a0=wave_reduce(a0); a1=wave_reduce(a1); a2=wave_reduce(a2); a3=wave_reduce(a3);
    float gi=a0+bias[0], gf=a1+bias[1], gg=a2+bias[2], go=a3+bias[3];
    c = sigmoidf_(gf)*c + sigmoidf_(gi)*tanhf(gg);
    float hn = sigmoidf_(go)*tanhf(c);
    if(lane==0){
      __hip_atomic_store(hbuf+((t+1)&1)*HCd+j,hn,__ATOMIC_RELAXED,__HIP_MEMORY_SCOPE_AGENT);
      if(t==NSE-1){ hT[j]=hn; cT[j]=c; }
    }
    gbar(ctr,(unsigned)(t+1)*PB);
    const float* src=hbuf+((t+1)&1)*HCd;
    for(int i=tid;i<HCd;i+=PT)
      hlds[i]=__hip_atomic_load(src+i,__ATOMIC_RELAXED,__HIP_MEMORY_SCOPE_AGENT);
    __syncthreads();
  }
}

// ---------------- VAE heads ----------------
__global__ __launch_bounds__(256) void k_head(
    const float* __restrict__ hT, const float* __restrict__ cT,
    const float* __restrict__ mhw, const float* __restrict__ mhb,
    const float* __restrict__ lhw, const float* __restrict__ lhb,
    const float* __restrict__ mcw, const float* __restrict__ mcb,
    const float* __restrict__ lcw, const float* __restrict__ lcb,
    const float* __restrict__ eps_h, const float* __restrict__ eps_c,
    const float* __restrict__ cemb, const int* __restrict__ condp,
    float* hbuf0, float* cbuf0, float* klh, float* klc)
{
  int i=blockIdx.x;                  // 0..767
  int tid=threadIdx.x, lane=tid&63, wv=tid>>6;
  __shared__ float sm[4];
  const float* Wm = (wv==0)?mhw:(wv==1)?lhw:(wv==2)?mcw:lcw;
  const float* vec = (wv<2)?hT:cT;
  const float* row = Wm+(size_t)i*HCd;
  float s=0.f;
  for(int k=lane;k<HCd;k+=64) s+=row[k]*vec[k];
  s=wave_reduce(s);
  if(lane==0) sm[wv]=s;
  __syncthreads();
  if(tid==0){
    float mh=sm[0]+mhb[i], lh=sm[1]+lhb[i];
    float mc=sm[2]+mcb[i], lc=sm[3]+lcb[i];
    float zh=eps_h[i]*expf(lh*0.5f)+mh;
    float zc=eps_c[i]*expf(lc*0.5f)+mc;
    hbuf0[i]=zh; cbuf0[i]=zc;
    klh[i]=0.5f*(mh*mh+expf(lh)-1.f-lh);
    klc[i]=0.5f*(mc*mc+expf(lc)-1.f-lc);
    if(i<Cc){
      float cd=cemb[condp[0]*Cc+i];
      hbuf0[Hh+i]=cd; cbuf0[Hh+i]=cd;
    }
  }
}

// ---------------- Decoder persistent scan ----------------
// t==0: gates = Wih x0 + b + W_hh_orig @ concat(z_h,cd);  cc = concat(z_c,cd)[j]
// t>=1: gates = Wih xt + b + cvec + Weff @ h_new_{t-1};   cc = fc_c(c_new_{t-1})[j] (j<768) else cd
__global__ __launch_bounds__(PT,2) void k_decoder(
    const int* __restrict__ tok, const int* __restrict__ condp,
    const float* __restrict__ emb, const float* __restrict__ cemb,
    const float* __restrict__ Wih, const float* __restrict__ WhhO,
    const float* __restrict__ Weff,
    const float* __restrict__ bih, const float* __restrict__ bhh,
    const float* __restrict__ cvec,
    const float* __restrict__ fccw, const float* __restrict__ fccb,
    float* hbuf, float* cbuf, float* __restrict__ Hmat, unsigned* ctr)
{
  __shared__ float hlds[HCd];
  __shared__ float clds[HCd];
  __shared__ int   tlds[LL];
  const int tid=threadIdx.x, lane=tid&63, wv=tid>>6;
  const int j=blockIdx.x*8+wv;
  const int cond=condp[0];
  for(int i=tid;i<LL;i+=PT) tlds[i]=tok[i];
  for(int i=tid;i<HCd;i+=PT){ hlds[i]=hbuf[i]; clds[i]=cbuf[i]; }
  __syncthreads();

  float wih[4][16], wef[4][16], fcc[16], bias[4], cv[4];
#pragma unroll
  for(int q=0;q<4;q++){
    const float* pw=Wih +(size_t)(q*HCd+j)*HCd+lane*16;
    const float* pe=Weff+(size_t)(q*HCd+j)*HCd+lane*16;
#pragma unroll
    for(int e=0;e<16;e+=4){
      *(float4*)&wih[q][e]=*(const float4*)(pw+e);
      *(float4*)&wef[q][e]=*(const float4*)(pe+e);
    }
    bias[q]=bih[q*HCd+j]+bhh[q*HCd+j];
    cv[q]=cvec[q*HCd+j];
  }
  if(j<Hh){
    const float* pf=fccw+(size_t)j*HCd+lane*16;
#pragma unroll
    for(int e=0;e<16;e+=4) *(float4*)&fcc[e]=*(const float4*)(pf+e);
  } else {
#pragma unroll
    for(int e=0;e<16;e++) fcc[e]=0.f;
  }
  const float fb =(j<Hh)?fccb[j]:0.f;
  const float cdj=(j>=Hh)?cemb[cond*Cc+(j-Hh)]:0.f;

  float x[16];
  { const float* px=emb+(size_t)tlds[0]*HCd+lane*16;
#pragma unroll
    for(int e=0;e<16;e+=4) *(float4*)&x[e]=*(const float4*)(px+e); }

  for(int t=0;t<NSD;t++){
    float a0=0,a1=0,a2=0,a3=0,a4=0;
#pragma unroll
    for(int e=0;e<16;e++){ float xv=x[e];
      a0+=wih[0][e]*xv; a1+=wih[1][e]*xv; a2+=wih[2][e]*xv; a3+=wih[3][e]*xv; }
    if(t+1<NSD){
      const float* px=emb+(size_t)tlds[t+1]*HCd+lane*16;
#pragma unroll
      for(int e=0;e<16;e+=4) *(float4*)&x[e]=*(const float4*)(px+e);
    }
    float hseg[16];
#pragma unroll
    for(int e=0;e<16;e+=4) *(float4*)&hseg[e]=*(float4*)&hlds[lane*16+e];
    if(t==0){
#pragma unroll
      for(int q=0;q<4;q++){
        const float* pw=WhhO+(size_t)(q*HCd+j)*HCd+lane*16;
        float s=0.f;
#pragma unroll
        for(int e=0;e<16;e+=4){
          float4 w4=*(const float4*)(pw+e);
          s+=w4.x*hseg[e]+w4.y*hseg[e+1]+w4.z*hseg[e+2]+w4.w*hseg[e+3];
        }
        if(q==0)a0+=s; else if(q==1)a1+=s; else if(q==2)a2+=s; else a3+=s;
      }
    } else {
      float cseg[16];
#pragma unroll
      for(int e=0;e<16;e+=4) *(float4*)&cseg[e]=*(float4*)&clds[lane*16+e];
#pragma unroll
      for(int e=0;e<16;e++){ float hv=hseg[e];
        a0+=wef[0][e]*hv; a1+=wef[1][e]*hv; a2+=wef[2][e]*hv; a3+=wef[3][e]*hv;
        a4+=fcc[e]*cseg[e]; }
    }
    a0=wave_reduce(a0); a1=wave_reduce(a1); a2=wave_reduce(a2);
    a3=wave_reduce(a3); a4=wave_reduce(a4);
    float add=(t>0)?1.f:0.f;
    float gi=a0+bias[0]+add*cv[0], gf=a1+bias[1]+add*cv[1];
    float gg=a2+bias[2]+add*cv[2], go=a3+bias[3]+add*cv[3];
    float cc=(t==0)?clds[j]:((j<Hh)?(a4+fb):cdj);
    float cn=sigmoidf_(gf)*cc + sigmoidf_(gi)*tanhf(gg);
    float hn=sigmoidf_(go)*tanhf(cn);
    if(lane==0){
      int nb=(t+1)&1;
      __hip_atomic_store(hbuf+nb*HCd+j,hn,__ATOMIC_RELAXED,__HIP_MEMORY_SCOPE_AGENT);
      __hip_atomic_store(cbuf+nb*HCd+j,cn,__ATOMIC_RELAXED,__HIP_MEMORY_SCOPE_AGENT);
      Hmat[(size_t)t*HCd+j]=hn;
    }
    gbar(ctr,(unsigned)(t+1)*PB);
    int nb=(t+1)&1;
    for(int i=tid;i<HCd;i+=PT){
      hlds[i]=__hip_atomic_load(hbuf+nb*HCd+i,__ATOMIC_RELAXED,__HIP_MEMORY_SCOPE_AGENT);
      clds[i]=__hip_atomic_load(cbuf+nb*HCd+i,__ATOMIC_RELAXED,__HIP_MEMORY_SCOPE_AGENT);
    }
    __syncthreads();
  }
}

// ---------------- logits GEMM (C = A·B^T + bias), A: Mx1024, B: 32000x1024 ----------------
__global__ __launch_bounds__(256) void k_gemm_tn_bias(
    const float* __restrict__ A, const float* __restrict__ B,
    const float* __restrict__ bias, float* __restrict__ Cm, int M)
{
  __shared__ float As[GBK][GBM];
  __shared__ float Bs[GBK][GBN];
  int tid=threadIdx.x;
  int m0=blockIdx.x*GBM, n0=blockIdx.y*GBN;
  int tm=tid>>4, tn=tid&15;
  float acc[8][8]={};
  for(int k0=0;k0<HCd;k0+=GBK){
#pragma unroll
    for(int u=0;u<2;u++){
      int idx=tid*2+u; int row=idx>>2, q=idx&3;
      float4 v={0,0,0,0};
      if(m0+row<M) v=*(const float4*)(A+(size_t)(m0+row)*HCd + k0+q*4);
      As[q*4+0][row]=v.x; As[q*4+1][row]=v.y; As[q*4+2][row]=v.z; As[q*4+3][row]=v.w;
      float4 w=*(const float4*)(B+(size_t)(n0+row)*HCd + k0+q*4);
      Bs[q*4+0][row]=w.x; Bs[q*4+1][row]=w.y; Bs[q*4+2][row]=w.z; Bs[q*4+3][row]=w.w;
    }
    __syncthreads();
#pragma unroll
    for(int kk=0;kk<GBK;kk++){
      float a[8],b[8];
      *(float4*)&a[0]=*(float4*)&As[kk][tm*8]; *(float4*)&a[4]=*(float4*)&As[kk][tm*8+4];
      *(float4*)&b[0]=*(float4*)&Bs[kk][tn*8]; *(float4*)&b[4]=*(float4*)&Bs[kk][tn*8+4];
#pragma unroll
      for(int i=0;i<8;i++)
#pragma unroll
        for(int j=0;j<8;j++) acc[i][j]+=a[i]*b[j];
    }
    __syncthreads();
  }
#pragma unroll
  for(int i=0;i<8;i++){
    int m=m0+tm*8+i; if(m>=M) continue;
#pragma unroll
    for(int j=0;j<8;j++){
      int n=n0+tn*8+j;
      Cm[(size_t)m*VSZ+n]=acc[i][j]+bias[n];
    }
  }
}

// per-row cross-entropy: ce[base+r] = logsumexp(row) - row[tgt]
__global__ __launch_bounds__(256) void k_ce(const float* __restrict__ logits,
    const int* __restrict__ tok, int base, float* __restrict__ ce)
{
  int r=blockIdx.x;
  const float* row=logits+(size_t)r*VSZ;
  int tid=threadIdx.x, lane=tid&63, wv=tid>>6;
  __shared__ float sm1[4];
  __shared__ float sm2[4];
  float m=-1e30f;
  for(int i=tid;i<VSZ;i+=256) m=fmaxf(m,row[i]);
#pragma unroll
  for(int o=32;o;o>>=1) m=fmaxf(m,__shfl_xor(m,o,64));
  if(lane==0) sm1[wv]=m;
  __syncthreads();
  m=fmaxf(fmaxf(sm1[0],sm1[1]),fmaxf(sm1[2],sm1[3]));
  float s=0.f;
  for(int i=tid;i<VSZ;i+=256) s+=__expf(row[i]-m);
  s=wave_reduce(s);
  if(lane==0) sm2[wv]=s;
  __syncthreads();
  if(tid==0){
    float tot=sm2[0]+sm2[1]+sm2[2]+sm2[3];
    int tgt=tok[base+r+1];
    ce[base+r]=m+logf(tot)-row[tgt];
  }
}

__global__ __launch_bounds__(256) void k_final(const float* __restrict__ ce,
    const float* __restrict__ klh, const float* __restrict__ klc,
    const float* __restrict__ kldw, float* __restrict__ outp)
{
  int tid=threadIdx.x, lane=tid&63, wv=tid>>6;
  float s0=0,s1=0,s2=0;
  for(int i=tid;i<NSD;i+=256) s0+=ce[i];
  for(int i=tid;i<Hh;i+=256){ s1+=klh[i]; s2+=klc[i]; }
  s0=wave_reduce(s0); s1=wave_reduce(s1); s2=wave_reduce(s2);
  __shared__ float sm[3][4];
  if(lane==0){ sm[0][wv]=s0; sm[1][wv]=s1; sm[2][wv]=s2; }
  __syncthreads();
  if(tid==0){
    float ces=sm[0][0]+sm[0][1]+sm[0][2]+sm[0][3];
    float kh =sm[1][0]+sm[1][1]+sm[1][2]+sm[1][3];
    float kc =sm[2][0]+sm[2][1]+sm[2][2]+sm[2][3];
    float rec=ces/(float)NSD;
    outp[0]=rec+(kh+kc)*kldw[0];
    outp[1]=rec; outp[2]=kh; outp[3]=kc;
  }
}

extern "C" void kernel_launch(void* const* d_in, const int* in_sizes, int n_in,
                              void* d_out, int out_size, void* d_ws, size_t ws_size,
                              hipStream_t stream) {
  const int*   tok   =(const int*)  d_in[0];
  const int*   cond  =(const int*)  d_in[1];
  const float* eps_h =(const float*)d_in[2];
  const float* eps_c =(const float*)d_in[3];
  const float* kldw  =(const float*)d_in[4];
  const float* enc_embed=(const float*)d_in[5];
  const float* enc_cemb =(const float*)d_in[6];
  const float* enc_Wih  =(const float*)d_in[7];
  const float* enc_Whh  =(const float*)d_in[8];
  const float* enc_bih  =(const float*)d_in[9];
  const float* enc_bhh  =(const float*)d_in[10];
  const float* fc_mh_w=(const float*)d_in[11];
  const float* fc_mh_b=(const float*)d_in[12];
  const float* fc_lh_w=(const float*)d_in[13];
  const float* fc_lh_b=(const float*)d_in[14];
  const float* fc_mc_w=(const float*)d_in[15];
  const float* fc_mc_b=(const float*)d_in[16];
  const float* fc_lc_w=(const float*)d_in[17];
  const float* fc_lc_b=(const float*)d_in[18];
  const float* dec_embed=(const float*)d_in[19];
  const float* dec_cemb =(const float*)d_in[20];
  const float* dec_Wih  =(const float*)d_in[21];
  const float* dec_Whh  =(const float*)d_in[22];
  const float* dec_bih  =(const float*)d_in[23];
  const float* dec_bhh  =(const float*)d_in[24];
  const float* fc_h_w=(const float*)d_in[25];
  const float* fc_h_b=(const float*)d_in[26];
  const float* fc_c_w=(const float*)d_in[27];
  const float* fc_c_b=(const float*)d_in[28];
  const float* out_w=(const float*)d_in[29];
  const float* out_b=(const float*)d_in[30];

  float* ws=(float*)d_ws;
  size_t off=16;                    // [0..3]: barrier counters
  unsigned* ctrs=(unsigned*)ws;
  float* cvec=ws+off; off+=G4;
  float* Weff=ws+off; off+=(size_t)G4*HCd;
  float* hbuf=ws+off; off+=2*HCd;
  float* cbuf=ws+off; off+=2*HCd;
  float* hT  =ws+off; off+=HCd;
  float* cT  =ws+off; off+=HCd;
  float* klh =ws+off; off+=Hh;
  float* klc =ws+off; off+=Hh;
  float* Hmat=ws+off; off+=(size_t)NSD*HCd;
  float* ce  =ws+off; off+=2048;
  size_t avail=ws_size/4;
  int chunk=256;
  if(off+ (size_t)chunk*VSZ > avail){
    size_t rem=(avail>off)?(avail-off):0;
    chunk=(int)(rem/(size_t)VSZ);
    if(chunk<1) chunk=1;
    if(chunk>256) chunk=256;
  }
  float* lbuf=ws+off;

  k_init<<<1,64,0,stream>>>(ctrs);
  k_dconst<<<64,256,0,stream>>>(dec_Whh,fc_h_b,dec_cemb,cond,cvec);
  { dim3 g(G4/GBM, HCd/GBN);
    k_weff<<<g,256,0,stream>>>(dec_Whh,fc_h_w,Weff); }
  k_encoder<<<PB,PT,0,stream>>>(tok,cond,enc_embed,enc_cemb,enc_Wih,enc_Whh,
                                enc_bih,enc_bhh,hbuf,hT,cT,ctrs+0);
  k_head<<<Hh,256,0,stream>>>(hT,cT,fc_mh_w,fc_mh_b,fc_lh_w,fc_lh_b,
                              fc_mc_w,fc_mc_b,fc_lc_w,fc_lc_b,
                              eps_h,eps_c,dec_cemb,cond,hbuf,cbuf,klh,klc);
  k_decoder<<<PB,PT,0,stream>>>(tok,cond,dec_embed,dec_cemb,dec_Wih,dec_Whh,Weff,
                                dec_bih,dec_bhh,cvec,fc_c_w,fc_c_b,
                                hbuf,cbuf,Hmat,ctrs+1);
  for(int base=0;base<NSD;base+=chunk){
    int rows=NSD-base; if(rows>chunk) rows=chunk;
    dim3 g((rows+GBM-1)/GBM, VSZ/GBN);
    k_gemm_tn_bias<<<g,256,0,stream>>>(Hmat+(size_t)base*HCd,out_w,out_b,lbuf,rows);
    k_ce<<<rows,256,0,stream>>>(lbuf,tok,base,ce);
  }
  k_final<<<1,256,0,stream>>>(ce,klh,klc,kldw,(float*)d_out);
}

// Round 2
// 27409.570 us; speedup vs baseline: 3.3848x; 3.3848x over previous
//
#include <hip/hip_runtime.h>
#include <math.h>

// Problem sizes (fixed)
#define VSZ 32000
#define Hh  768
#define Cc  256
#define HCd 1024
#define G4  4096
#define LL  2048
#define NSE 2046   // encoder steps
#define NSD 2047   // decoder steps

// Persistent scan shape: 64 blocks x 512 threads (8 waves) = 512 waves,
// each wave owns 2 output elements (8 gate rows). Co-resident on 256 CUs.
#define EB 64
#define ET 512

__device__ __forceinline__ float sigmoidf_(float x){ return 1.0f/(1.0f+expf(-x)); }

__device__ __forceinline__ float wave_reduce(float v){
#pragma unroll
  for(int o=32;o;o>>=1) v += __shfl_xor(v,o,64);
  return v;
}

// init: zero both flag arrays, stage encoder h0 = [0, cemb]
__global__ void k_init2(unsigned* arrE, unsigned* arrD, float* eh0,
                        const float* __restrict__ cemb, const int* __restrict__ condp){
  int tid=threadIdx.x;
  if(tid<64){ arrE[tid*64]=0u; arrD[tid*64]=0u; }
  int cond=condp[0];
  for(int i=tid;i<HCd;i+=256) eh0[i]=(i<Hh)?0.f:cemb[cond*Cc+(i-Hh)];
}

// dec_const[r] = dec_W_hh[r,0:768]·fc_h_b + dec_W_hh[r,768:1024]·cd
__global__ __launch_bounds__(256) void k_dconst(const float* __restrict__ Whh,
    const float* __restrict__ fhb, const float* __restrict__ cemb,
    const int* __restrict__ condp, float* __restrict__ cvec){
  int lane=threadIdx.x&63, wv=threadIdx.x>>6;
  int wgid=blockIdx.x*4+wv;
  int cond=condp[0];
  for(int r=wgid;r<G4;r+=256){
    const float* row=Whh+(size_t)r*HCd;
    float s=0.f;
    for(int k=lane;k<Hh;k+=64) s+=row[k]*fhb[k];
    for(int k=lane;k<Cc;k+=64) s+=row[Hh+k]*cemb[cond*Cc+k];
    s=wave_reduce(s);
    if(lane==0) cvec[r]=s;
  }
}

#define GBM 128
#define GBN 128
#define GBK 16

// Weff[r,k] = sum_{i<768} dec_W_hh[r,i]*fc_h_w[i,k]   (M=4096,N=1024,K=768)
__global__ __launch_bounds__(256) void k_weff(const float* __restrict__ A,
    const float* __restrict__ B, float* __restrict__ Cm){
  __shared__ float As[GBK][GBM];
  __shared__ float Bs[GBK][GBN];
  int tid=threadIdx.x;
  int m0=blockIdx.x*GBM, n0=blockIdx.y*GBN;
  int tm=tid>>4, tn=tid&15;
  float acc[8][8]={};
  for(int k0=0;k0<Hh;k0+=GBK){
#pragma unroll
    for(int u=0;u<2;u++){
      int idx=tid*2+u;
      int row=idx>>2, q=idx&3;
      float4 v=*(const float4*)(A+(size_t)(m0+row)*HCd + k0+q*4);
      As[q*4+0][row]=v.x; As[q*4+1][row]=v.y; As[q*4+2][row]=v.z; As[q*4+3][row]=v.w;
      int kk=idx>>5, nc=idx&31;
      float4 w=*(const float4*)(B+(size_t)(k0+kk)*HCd + n0+nc*4);
      *(float4*)&Bs[kk][nc*4]=w;
    }
    __syncthreads();
#pragma unroll
    for(int kk=0;kk<GBK;kk++){
      float a[8],b[8];
      *(float4*)&a[0]=*(float4*)&As[kk][tm*8]; *(float4*)&a[4]=*(float4*)&As[kk][tm*8+4];
      *(float4*)&b[0]=*(float4*)&Bs[kk][tn*8]; *(float4*)&b[4]=*(float4*)&Bs[kk][tn*8+4];
#pragma unroll
      for(int i=0;i<8;i++)
#pragma unroll
        for(int j=0;j<8;j++) acc[i][j]+=a[i]*b[j];
    }
    __syncthreads();
  }
#pragma unroll
  for(int i=0;i<8;i++)
#pragma unroll
    for(int j=0;j<8;j++)
      Cm[(size_t)(m0+tm*8+i)*HCd + n0+tn*8+j]=acc[i][j];
}

// X[m][n] = emb[tok[m+tshift]] · Wih_row(n) + b1[n]+b2[n]   (N=4096, K=1024)
__global__ __launch_bounds__(256) void k_xgemm(
    const float* __restrict__ emb, const float* __restrict__ Wih,
    const float* __restrict__ b1, const float* __restrict__ b2,
    const int* __restrict__ tok, int tshift, int M,
    float* __restrict__ X)
{
  __shared__ float As[GBK][GBM];
  __shared__ float Bs[GBK][GBN];
  int tid=threadIdx.x;
  int m0=blockIdx.x*GBM, n0=blockIdx.y*GBN;
  int tm=tid>>4, tn=tid&15;
  int arow=m0+(tid>>1);
  int atok=(arow<M)?tok[arow+tshift]:0;
  const float* abase=emb+(size_t)atok*HCd+(tid&1)*8;
  const float* bbase=Wih+(size_t)(n0+(tid>>1))*HCd+(tid&1)*8;
  int srow=tid>>1;
  float acc[8][8]={};
  for(int k0=0;k0<HCd;k0+=GBK){
#pragma unroll
    for(int u=0;u<2;u++){
      int q=2*(tid&1)+u;
      float4 v={0,0,0,0};
      if(arow<M) v=*(const float4*)(abase+k0+u*4);
      As[q*4+0][srow]=v.x; As[q*4+1][srow]=v.y; As[q*4+2][srow]=v.z; As[q*4+3][srow]=v.w;
      float4 w=*(const float4*)(bbase+k0+u*4);
      Bs[q*4+0][srow]=w.x; Bs[q*4+1][srow]=w.y; Bs[q*4+2][srow]=w.z; Bs[q*4+3][srow]=w.w;
    }
    __syncthreads();
#pragma unroll
    for(int kk=0;kk<GBK;kk++){
      float a[8],b[8];
      *(float4*)&a[0]=*(float4*)&As[kk][tm*8]; *(float4*)&a[4]=*(float4*)&As[kk][tm*8+4];
      *(float4*)&b[0]=*(float4*)&Bs[kk][tn*8]; *(float4*)&b[4]=*(float4*)&Bs[kk][tn*8+4];
#pragma unroll
      for(int i=0;i<8;i++)
#pragma unroll
        for(int j=0;j<8;j++) acc[i][j]+=a[i]*b[j];
    }
    __syncthreads();
  }
#pragma unroll
  for(int i=0;i<8;i++){
    int m=m0+tm*8+i; if(m>=M) continue;
#pragma unroll
    for(int j=0;j<8;j++){
      int n=n0+tn*8+j;
      X[(size_t)m*G4+n]=acc[i][j]+b1[n]+b2[n];
    }
  }
}

// ---------------- Encoder persistent scan ----------------
__global__ __launch_bounds__(ET,2) void k_enc2(
    const float* __restrict__ Xg,     // [NSE][4096], bias folded in
    const float* __restrict__ Whh,    // [4096][1024]
    float* eh,                        // [2][1024]
    float* hT, float* cT, unsigned* arr)
{
  __shared__ float hlds[HCd];
  const int tid=threadIdx.x, lane=tid&63, wv=tid>>6;
  const int wid=blockIdx.x*8+wv;
  const int j0=wid*2, j1=j0+1;
  float w[8][16];
#pragma unroll
  for(int q=0;q<4;q++)
#pragma unroll
    for(int jj=0;jj<2;jj++){
      const float* p=Whh+(size_t)(q*HCd+j0+jj)*HCd+lane;
#pragma unroll
      for(int e=0;e<16;e++) w[q*2+jj][e]=p[(size_t)e*64];
    }
  float xg[8];
#pragma unroll
  for(int r=0;r<8;r++) xg[r]=Xg[(r>>1)*HCd+j0+(r&1)];
  float c0=0.f,c1=0.f;

  for(int t=0;t<NSE;t++){
    if(t>0){
      if(tid<EB){
        while(__hip_atomic_load(arr+tid*64,__ATOMIC_ACQUIRE,__HIP_MEMORY_SCOPE_AGENT)<(unsigned)t)
          __builtin_amdgcn_s_sleep(1);
      }
      __syncthreads();
    }
    const float* src=eh+(t&1)*HCd;
    { int i=tid*2;
      float a=__hip_atomic_load(src+i,__ATOMIC_RELAXED,__HIP_MEMORY_SCOPE_AGENT);
      float b=__hip_atomic_load(src+i+1,__ATOMIC_RELAXED,__HIP_MEMORY_SCOPE_AGENT);
      hlds[i]=a; hlds[i+1]=b; }
    __syncthreads();
    if(t==0){ c0=hlds[j0]; c1=hlds[j1]; }   // h0 == c0
    float hseg[16];
#pragma unroll
    for(int e=0;e<16;e++) hseg[e]=hlds[lane+64*e];
    float d[8];
#pragma unroll
    for(int r=0;r<8;r++){ float s=0.f;
#pragma unroll
      for(int e=0;e<16;e++) s+=w[r][e]*hseg[e];
      d[r]=s; }
#pragma unroll
    for(int r=0;r<8;r++) d[r]=wave_reduce(d[r]);
    float gi0=d[0]+xg[0], gi1=d[1]+xg[1];
    float gf0=d[2]+xg[2], gf1=d[3]+xg[3];
    float gg0=d[4]+xg[4], gg1=d[5]+xg[5];
    float go0=d[6]+xg[6], go1=d[7]+xg[7];
    c0=sigmoidf_(gf0)*c0+sigmoidf_(gi0)*tanhf(gg0);
    float h0=sigmoidf_(go0)*tanhf(c0);
    c1=sigmoidf_(gf1)*c1+sigmoidf_(gi1)*tanhf(gg1);
    float h1=sigmoidf_(go1)*tanhf(c1);
    float* dst=eh+((t+1)&1)*HCd;
    if(lane==0){
      __hip_atomic_store(dst+j0,h0,__ATOMIC_RELAXED,__HIP_MEMORY_SCOPE_AGENT);
      __hip_atomic_store(dst+j1,h1,__ATOMIC_RELAXED,__HIP_MEMORY_SCOPE_AGENT);
      if(t==NSE-1){ hT[j0]=h0; hT[j1]=h1; cT[j0]=c0; cT[j1]=c1; }
    }
    if(t+1<NSE){
      const float* px=Xg+(size_t)(t+1)*G4;
#pragma unroll
      for(int r=0;r<8;r++) xg[r]=px[(r>>1)*HCd+j0+(r&1)];
    }
    __syncthreads();
    if(tid==0){
      __threadfence();
      __hip_atomic_store(arr+blockIdx.x*64,(unsigned)(t+1),__ATOMIC_RELEASE,__HIP_MEMORY_SCOPE_AGENT);
    }
  }
}

// ---------------- VAE heads ----------------
__global__ __launch_bounds__(256) void k_head(
    const float* __restrict__ hT, const float* __restrict__ cT,
    const float* __restrict__ mhw, const float* __restrict__ mhb,
    const float* __restrict__ lhw, const float* __restrict__ lhb,
    const float* __restrict__ mcw, const float* __restrict__ mcb,
    const float* __restrict__ lcw, const float* __restrict__ lcb,
    const float* __restrict__ eps_h, const float* __restrict__ eps_c,
    const float* __restrict__ cemb, const int* __restrict__ condp,
    float* zh, float* zc, float* klh, float* klc)
{
  int i=blockIdx.x;
  int tid=threadIdx.x, lane=tid&63, wv=tid>>6;
  __shared__ float sm[4];
  const float* Wm=(wv==0)?mhw:(wv==1)?lhw:(wv==2)?mcw:lcw;
  const float* vec=(wv<2)?hT:cT;
  const float* row=Wm+(size_t)i*HCd;
  float s=0.f;
  for(int k=lane;k<HCd;k+=64) s+=row[k]*vec[k];
  s=wave_reduce(s);
  if(lane==0) sm[wv]=s;
  __syncthreads();
  if(tid==0){
    float mh=sm[0]+mhb[i], lh=sm[1]+lhb[i];
    float mc=sm[2]+mcb[i], lc=sm[3]+lcb[i];
    float zhv=eps_h[i]*expf(lh*0.5f)+mh;
    float zcv=eps_c[i]*expf(lc*0.5f)+mc;
    zh[i]=zhv; zc[i]=zcv;
    klh[i]=0.5f*(mh*mh+expf(lh)-1.f-lh);
    klc[i]=0.5f*(mc*mc+expf(lc)-1.f-lc);
    if(i<Cc){
      float cd=cemb[condp[0]*Cc+i];
      zh[Hh+i]=cd; zc[Hh+i]=cd;
    }
  }
}

// decoder step 0: gates = Xdec[0] + WhhO·concat(zh,cd); cc = concat(zc,cd)[j]
__global__ __launch_bounds__(256) void k_dec0(
    const float* __restrict__ Xg, const float* __restrict__ WhhO,
    const float* __restrict__ zh, const float* __restrict__ zc,
    float* dh, float* dc, float* Hmat)
{
  int tid=threadIdx.x, lane=tid&63, wv=tid>>6;
  int j=blockIdx.x*4+wv;
  float hseg[16];
#pragma unroll
  for(int e=0;e<16;e++) hseg[e]=zh[lane+64*e];
  float g[4];
#pragma unroll
  for(int q=0;q<4;q++){
    const float* p=WhhO+(size_t)(q*HCd+j)*HCd+lane;
    float s=0.f;
#pragma unroll
    for(int e=0;e<16;e++) s+=p[(size_t)e*64]*hseg[e];
    s=wave_reduce(s);
    g[q]=s+Xg[q*HCd+j];
  }
  float cc=zc[j];
  float cn=sigmoidf_(g[1])*cc+sigmoidf_(g[0])*tanhf(g[2]);
  float hn=sigmoidf_(g[3])*tanhf(cn);
  if(lane==0){ dh[HCd+j]=hn; dc[HCd+j]=cn; Hmat[j]=hn; }
}

// ---------------- Decoder persistent scan (t = 1..NSD-1) ----------------
__global__ __launch_bounds__(ET,2) void k_dec2(
    const float* __restrict__ Xg,     // [NSD][4096], bias folded
    const float* __restrict__ Weff,
    const float* __restrict__ cvec,
    const float* __restrict__ fccw, const float* __restrict__ fccb,
    const float* __restrict__ cemb, const int* __restrict__ condp,
    float* dh, float* dc, float* __restrict__ Hmat, unsigned* arr)
{
  __shared__ float hlds[HCd];
  __shared__ float clds[HCd];
  const int tid=threadIdx.x, lane=tid&63, wv=tid>>6;
  const int wid=blockIdx.x*8+wv;
  const int j0=wid*2, j1=j0+1;
  float w[8][16];
#pragma unroll
  for(int q=0;q<4;q++)
#pragma unroll
    for(int jj=0;jj<2;jj++){
      const float* p=Weff+(size_t)(q*HCd+j0+jj)*HCd+lane;
#pragma unroll
      for(int e=0;e<16;e++) w[q*2+jj][e]=p[(size_t)e*64];
    }
  const bool hasf=(j0<Hh);
  float fcc0[16], fcc1[16];
  if(hasf){
    const float* p0=fccw+(size_t)j0*HCd+lane;
    const float* p1=fccw+(size_t)j1*HCd+lane;
#pragma unroll
    for(int e=0;e<16;e++){ fcc0[e]=p0[(size_t)e*64]; fcc1[e]=p1[(size_t)e*64]; }
  } else {
#pragma unroll
    for(int e=0;e<16;e++){ fcc0[e]=0.f; fcc1[e]=0.f; }
  }
  float fb0=hasf?fccb[j0]:0.f, fb1=hasf?fccb[j1]:0.f;
  int cond=condp[0];
  float cd0=hasf?0.f:cemb[cond*Cc+(j0-Hh)];
  float cd1=hasf?0.f:cemb[cond*Cc+(j1-Hh)];
  float cv[8];
#pragma unroll
  for(int r=0;r<8;r++) cv[r]=cvec[(r>>1)*HCd+j0+(r&1)];
  float xg[8];
  { const float* px=Xg+(size_t)1*G4;
#pragma unroll
    for(int r=0;r<8;r++) xg[r]=px[(r>>1)*HCd+j0+(r&1)]; }

  for(int t=1;t<NSD;t++){
    if(t>1){
      if(tid<EB){
        while(__hip_atomic_load(arr+tid*64,__ATOMIC_ACQUIRE,__HIP_MEMORY_SCOPE_AGENT)<(unsigned)(t-1))
          __builtin_amdgcn_s_sleep(1);
      }
      __syncthreads();
    }
    const float* sh=dh+(t&1)*HCd;
    const float* sc=dc+(t&1)*HCd;
    { int i=tid*2;
      float a=__hip_atomic_load(sh+i,__ATOMIC_RELAXED,__HIP_MEMORY_SCOPE_AGENT);
      float b=__hip_atomic_load(sh+i+1,__ATOMIC_RELAXED,__HIP_MEMORY_SCOPE_AGENT);
      float e=__hip_atomic_load(sc+i,__ATOMIC_RELAXED,__HIP_MEMORY_SCOPE_AGENT);
      float f=__hip_atomic_load(sc+i+1,__ATOMIC_RELAXED,__HIP_MEMORY_SCOPE_AGENT);
      hlds[i]=a; hlds[i+1]=b; clds[i]=e; clds[i+1]=f; }
    __syncthreads();
    float hseg[16], cseg[16];
#pragma unroll
    for(int e=0;e<16;e++){ hseg[e]=hlds[lane+64*e]; cseg[e]=clds[lane+64*e]; }
    float d[8]; float s8=0.f, s9=0.f;
#pragma unroll
    for(int r=0;r<8;r++){ float s=0.f;
#pragma unroll
      for(int e=0;e<16;e++) s+=w[r][e]*hseg[e];
      d[r]=s; }
    if(hasf){
#pragma unroll
      for(int e=0;e<16;e++){ s8+=fcc0[e]*cseg[e]; s9+=fcc1[e]*cseg[e]; }
    }
#pragma unroll
    for(int r=0;r<8;r++) d[r]=wave_reduce(d[r]);
    s8=wave_reduce(s8); s9=wave_reduce(s9);
    float gi0=d[0]+xg[0]+cv[0], gi1=d[1]+xg[1]+cv[1];
    float gf0=d[2]+xg[2]+cv[2], gf1=d[3]+xg[3]+cv[3];
    float gg0=d[4]+xg[4]+cv[4], gg1=d[5]+xg[5]+cv[5];
    float go0=d[6]+xg[6]+cv[6], go1=d[7]+xg[7]+cv[7];
    float cc0=hasf?(s8+fb0):cd0;
    float cc1=hasf?(s9+fb1):cd1;
    float cn0=sigmoidf_(gf0)*cc0+sigmoidf_(gi0)*tanhf(gg0);
    float hn0=sigmoidf_(go0)*tanhf(cn0);
    float cn1=sigmoidf_(gf1)*cc1+sigmoidf_(gi1)*tanhf(gg1);
    float hn1=sigmoidf_(go1)*tanhf(cn1);
    float* wh=dh+((t+1)&1)*HCd;
    float* wc=dc+((t+1)&1)*HCd;
    if(lane==0){
      __hip_atomic_store(wh+j0,hn0,__ATOMIC_RELAXED,__HIP_MEMORY_SCOPE_AGENT);
      __hip_atomic_store(wh+j1,hn1,__ATOMIC_RELAXED,__HIP_MEMORY_SCOPE_AGENT);
      __hip_atomic_store(wc+j0,cn0,__ATOMIC_RELAXED,__HIP_MEMORY_SCOPE_AGENT);
      __hip_atomic_store(wc+j1,cn1,__ATOMIC_RELAXED,__HIP_MEMORY_SCOPE_AGENT);
      Hmat[(size_t)t*HCd+j0]=hn0; Hmat[(size_t)t*HCd+j1]=hn1;
    }
    if(t+1<NSD){
      const float* px=Xg+(size_t)(t+1)*G4;
#pragma unroll
      for(int r=0;r<8;r++) xg[r]=px[(r>>1)*HCd+j0+(r&1)];
    }
    __syncthreads();
    if(tid==0){
      __threadfence();
      __hip_atomic_store(arr+blockIdx.x*64,(unsigned)t,__ATOMIC_RELEASE,__HIP_MEMORY_SCOPE_AGENT);
    }
  }
}

// ---------------- logits GEMM (C = A·B^T + bias) ----------------
__global__ __launch_bounds__(256) void k_gemm_tn_bias(
    const float* __restrict__ A, const float* __restrict__ B,
    const float* __restrict__ bias, float* __restrict__ Cm, int M)
{
  __shared__ float As[GBK][GBM];
  __shared__ float Bs[GBK][GBN];
  int tid=threadIdx.x;
  int m0=blockIdx.x*GBM, n0=blockIdx.y*GBN;
  int tm=tid>>4, tn=tid&15;
  float acc[8][8]={};
  for(int k0=0;k0<HCd;k0+=GBK){
#pragma unroll
    for(int u=0;u<2;u++){
      int idx=tid*2+u; int row=idx>>2, q=idx&3;
      float4 v={0,0,0,0};
      if(m0+row<M) v=*(const float4*)(A+(size_t)(m0+row)*HCd + k0+q*4);
      As[q*4+0][row]=v.x; As[q*4+1][row]=v.y; As[q*4+2][row]=v.z; As[q*4+3][row]=v.w;
      float4 w=*(const float4*)(B+(size_t)(n0+row)*HCd + k0+q*4);
      Bs[q*4+0][row]=w.x; Bs[q*4+1][row]=w.y; Bs[q*4+2][row]=w.z; Bs[q*4+3][row]=w.w;
    }
    __syncthreads();
#pragma unroll
    for(int kk=0;kk<GBK;kk++){
      float a[8],b[8];
      *(float4*)&a[0]=*(float4*)&As[kk][tm*8]; *(float4*)&a[4]=*(float4*)&As[kk][tm*8+4];
      *(float4*)&b[0]=*(float4*)&Bs[kk][tn*8]; *(float4*)&b[4]=*(float4*)&Bs[kk][tn*8+4];
#pragma unroll
      for(int i=0;i<8;i++)
#pragma unroll
        for(int j=0;j<8;j++) acc[i][j]+=a[i]*b[j];
    }
    __syncthreads();
  }
#pragma unroll
  for(int i=0;i<8;i++){
    int m=m0+tm*8+i; if(m>=M) continue;
#pragma unroll
    for(int j=0;j<8;j++){
      int n=n0+tn*8+j;
      Cm[(size_t)m*VSZ+n]=acc[i][j]+bias[n];
    }
  }
}

// per-row cross-entropy
__global__ __launch_bounds__(256) void k_ce(const float* __restrict__ logits,
    const int* __restrict__ tok, int base, float* __restrict__ ce)
{
  int r=blockIdx.x;
  const float* row=logits+(size_t)r*VSZ;
  int tid=threadIdx.x, lane=tid&63, wv=tid>>6;
  __shared__ float sm1[4];
  __shared__ float sm2[4];
  float m=-1e30f;
  for(int i=tid;i<VSZ;i+=256) m=fmaxf(m,row[i]);
#pragma unroll
  for(int o=32;o;o>>=1) m=fmaxf(m,__shfl_xor(m,o,64));
  if(lane==0) sm1[wv]=m;
  __syncthreads();
  m=fmaxf(fmaxf(sm1[0],sm1[1]),fmaxf(sm1[2],sm1[3]));
  float s=0.f;
  for(int i=tid;i<VSZ;i+=256) s+=__expf(row[i]-m);
  s=wave_reduce(s);
  if(lane==0) sm2[wv]=s;
  __syncthreads();
  if(tid==0){
    float tot=sm2[0]+sm2[1]+sm2[2]+sm2[3];
    int tgt=tok[base+r+1];
    ce[base+r]=m+logf(tot)-row[tgt];
  }
}

__global__ __launch_bounds__(256) void k_final(const float* __restrict__ ce,
    const float* __restrict__ klh, const float* __restrict__ klc,
    const float* __restrict__ kldw, float* __restrict__ outp)
{
  int tid=threadIdx.x, lane=tid&63, wv=tid>>6;
  float s0=0,s1=0,s2=0;
  for(int i=tid;i<NSD;i+=256) s0+=ce[i];
  for(int i=tid;i<Hh;i+=256){ s1+=klh[i]; s2+=klc[i]; }
  s0=wave_reduce(s0); s1=wave_reduce(s1); s2=wave_reduce(s2);
  __shared__ float sm[3][4];
  if(lane==0){ sm[0][wv]=s0; sm[1][wv]=s1; sm[2][wv]=s2; }
  __syncthreads();
  if(tid==0){
    float ces=sm[0][0]+sm[0][1]+sm[0][2]+sm[0][3];
    float kh =sm[1][0]+sm[1][1]+sm[1][2]+sm[1][3];
    float kc =sm[2][0]+sm[2][1]+sm[2][2]+sm[2][3];
    float rec=ces/(float)NSD;
    outp[0]=rec+(kh+kc)*kldw[0];
    outp[1]=rec; outp[2]=kh; outp[3]=kc;
  }
}

extern "C" void kernel_launch(void* const* d_in, const int* in_sizes, int n_in,
                              void* d_out, int out_size, void* d_ws, size_t ws_size,
                              hipStream_t stream) {
  const int*   tok   =(const int*)  d_in[0];
  const int*   cond  =(const int*)  d_in[1];
  const float* eps_h =(const float*)d_in[2];
  const float* eps_c =(const float*)d_in[3];
  const float* kldw  =(const float*)d_in[4];
  const float* enc_embed=(const float*)d_in[5];
  const float* enc_cemb =(const float*)d_in[6];
  const float* enc_Wih  =(const float*)d_in[7];
  const float* enc_Whh  =(const float*)d_in[8];
  const float* enc_bih  =(const float*)d_in[9];
  const float* enc_bhh  =(const float*)d_in[10];
  const float* fc_mh_w=(const float*)d_in[11];
  const float* fc_mh_b=(const float*)d_in[12];
  const float* fc_lh_w=(const float*)d_in[13];
  const float* fc_lh_b=(const float*)d_in[14];
  const float* fc_mc_w=(const float*)d_in[15];
  const float* fc_mc_b=(const float*)d_in[16];
  const float* fc_lc_w=(const float*)d_in[17];
  const float* fc_lc_b=(const float*)d_in[18];
  const float* dec_embed=(const float*)d_in[19];
  const float* dec_cemb =(const float*)d_in[20];
  const float* dec_Wih  =(const float*)d_in[21];
  const float* dec_Whh  =(const float*)d_in[22];
  const float* dec_bih  =(const float*)d_in[23];
  const float* dec_bhh  =(const float*)d_in[24];
  const float* fc_h_w=(const float*)d_in[25];
  const float* fc_h_b=(const float*)d_in[26];
  const float* fc_c_w=(const float*)d_in[27];
  const float* fc_c_b=(const float*)d_in[28];
  const float* out_w=(const float*)d_in[29];
  const float* out_b=(const float*)d_in[30];

  float* ws=(float*)d_ws;
  size_t off=0;
  unsigned* arrE=(unsigned*)(ws+off); off+=4096;   // 64 flags, 256B apart
  unsigned* arrD=(unsigned*)(ws+off); off+=4096;
  float* cvec=ws+off; off+=G4;
  float* Weff=ws+off; off+=(size_t)G4*HCd;
  float* eh  =ws+off; off+=2*HCd;
  float* dh  =ws+off; off+=2*HCd;
  float* dc  =ws+off; off+=2*HCd;
  float* hT  =ws+off; off+=HCd;
  float* cT  =ws+off; off+=HCd;
  float* zh  =ws+off; off+=HCd;
  float* zc  =ws+off; off+=HCd;
  float* klh =ws+off; off+=Hh;
  float* klc =ws+off; off+=Hh;
  float* Hmat=ws+off; off+=(size_t)NSD*HCd;
  float* ce  =ws+off; off+=2048;
  float* X   =ws+off;                       // shared region: Xenc / Xdec / lbuf
  size_t avail=ws_size/4;
  size_t region=(avail>off)?(avail-off):0;
  int chunk=256;
  if((size_t)chunk*VSZ>region){
    chunk=(int)(region/(size_t)VSZ);
    if(chunk<1) chunk=1;
  }
  float* lbuf=X;

  k_init2<<<1,256,0,stream>>>(arrE,arrD,eh,enc_cemb,cond);
  k_dconst<<<64,256,0,stream>>>(dec_Whh,fc_h_b,dec_cemb,cond,cvec);
  { dim3 g(G4/GBM, HCd/GBN);
    k_weff<<<g,256,0,stream>>>(dec_Whh,fc_h_w,Weff); }
  { dim3 g((NSE+GBM-1)/GBM, G4/GBN);        // Xenc
    k_xgemm<<<g,256,0,stream>>>(enc_embed,enc_Wih,enc_bih,enc_bhh,tok,1,NSE,X); }
  k_enc2<<<EB,ET,0,stream>>>(X,enc_Whh,eh,hT,cT,arrE);
  k_head<<<Hh,256,0,stream>>>(hT,cT,fc_mh_w,fc_mh_b,fc_lh_w,fc_lh_b,
                              fc_mc_w,fc_mc_b,fc_lc_w,fc_lc_b,
                              eps_h,eps_c,dec_cemb,cond,zh,zc,klh,klc);
  { dim3 g((NSD+GBM-1)/GBM, G4/GBN);        // Xdec (overwrites Xenc — encoder done)
    k_xgemm<<<g,256,0,stream>>>(dec_embed,dec_Wih,dec_bih,dec_bhh,tok,0,NSD,X); }
  k_dec0<<<256,256,0,stream>>>(X,dec_Whh,zh,zc,dh,dc,Hmat);
  k_dec2<<<EB,ET,0,stream>>>(X,Weff,cvec,fc_c_w,fc_c_b,dec_cemb,cond,dh,dc,Hmat,arrD);
  for(int base=0;base<NSD;base+=chunk){     // lbuf overlays X — decoder done
    int rows=NSD-base; if(rows>chunk) rows=chunk;
    dim3 g((rows+GBM-1)/GBM, VSZ/GBN);
    k_gemm_tn_bias<<<g,256,0,stream>>>(Hmat+(size_t)base*HCd,out_w,out_b,lbuf,rows);
    k_ce<<<rows,256,0,stream>>>(lbuf,tok,base,ce);
  }
  k_final<<<1,256,0,stream>>>(ce,klh,klc,kldw,(float*)d_out);
}

// Round 3
// 23126.381 us; speedup vs baseline: 4.0117x; 1.1852x over previous
//
#include <hip/hip_runtime.h>
#include <math.h>

// Problem sizes (fixed)
#define VSZ 32000
#define Hh  768
#define Cc  256
#define HCd 1024
#define G4  4096
#define LL  2048
#define NSE 2046   // encoder steps
#define NSD 2047   // decoder steps

// Persistent scan shape: 64 blocks x 512 threads (8 waves) = 512 waves,
// each wave owns 2 output elements (8 gate rows).
#define EB 64
#define ET 512

__device__ __forceinline__ float sigmoidf_(float x){ return 1.0f/(1.0f+expf(-x)); }

__device__ __forceinline__ float wave_reduce(float v){
#pragma unroll
  for(int o=32;o;o>>=1) v += __shfl_xor(v,o,64);
  return v;
}

// init: encoder S_0 into ehb[0] (parity 0), ehb[1] poisoned to parity 1
__global__ void k_init3(unsigned* ehb, const float* __restrict__ cemb,
                        const int* __restrict__ condp){
  int tid=threadIdx.x;
  int cond=condp[0];
  for(int i=tid;i<HCd;i+=256){
    float v=(i<Hh)?0.f:cemb[cond*Cc+(i-Hh)];
    ehb[i]=__float_as_uint(v)&~1u;   // S_0, parity 0
    ehb[HCd+i]=1u;                   // phase-1 slot: parity 1 (invalid for s=2)
  }
}

// dec_const[r] = dec_W_hh[r,0:768]·fc_h_b + dec_W_hh[r,768:1024]·cd
__global__ __launch_bounds__(256) void k_dconst(const float* __restrict__ Whh,
    const float* __restrict__ fhb, const float* __restrict__ cemb,
    const int* __restrict__ condp, float* __restrict__ cvec){
  int lane=threadIdx.x&63, wv=threadIdx.x>>6;
  int wgid=blockIdx.x*4+wv;
  int cond=condp[0];
  for(int r=wgid;r<G4;r+=256){
    const float* row=Whh+(size_t)r*HCd;
    float s=0.f;
    for(int k=lane;k<Hh;k+=64) s+=row[k]*fhb[k];
    for(int k=lane;k<Cc;k+=64) s+=row[Hh+k]*cemb[cond*Cc+k];
    s=wave_reduce(s);
    if(lane==0) cvec[r]=s;
  }
}

#define GBM 128
#define GBN 128
#define GBK 16

// Weff[r,k] = sum_{i<768} dec_W_hh[r,i]*fc_h_w[i,k]   (M=4096,N=1024,K=768)
__global__ __launch_bounds__(256) void k_weff(const float* __restrict__ A,
    const float* __restrict__ B, float* __restrict__ Cm){
  __shared__ float As[GBK][GBM];
  __shared__ float Bs[GBK][GBN];
  int tid=threadIdx.x;
  int m0=blockIdx.x*GBM, n0=blockIdx.y*GBN;
  int tm=tid>>4, tn=tid&15;
  float acc[8][8]={};
  for(int k0=0;k0<Hh;k0+=GBK){
#pragma unroll
    for(int u=0;u<2;u++){
      int idx=tid*2+u;
      int row=idx>>2, q=idx&3;
      float4 v=*(const float4*)(A+(size_t)(m0+row)*HCd + k0+q*4);
      As[q*4+0][row]=v.x; As[q*4+1][row]=v.y; As[q*4+2][row]=v.z; As[q*4+3][row]=v.w;
      int kk=idx>>5, nc=idx&31;
      float4 w=*(const float4*)(B+(size_t)(k0+kk)*HCd + n0+nc*4);
      *(float4*)&Bs[kk][nc*4]=w;
    }
    __syncthreads();
#pragma unroll
    for(int kk=0;kk<GBK;kk++){
      float a[8],b[8];
      *(float4*)&a[0]=*(float4*)&As[kk][tm*8]; *(float4*)&a[4]=*(float4*)&As[kk][tm*8+4];
      *(float4*)&b[0]=*(float4*)&Bs[kk][tn*8]; *(float4*)&b[4]=*(float4*)&Bs[kk][tn*8+4];
#pragma unroll
      for(int i=0;i<8;i++)
#pragma unroll
        for(int j=0;j<8;j++) acc[i][j]+=a[i]*b[j];
    }
    __syncthreads();
  }
#pragma unroll
  for(int i=0;i<8;i++)
#pragma unroll
    for(int j=0;j<8;j++)
      Cm[(size_t)(m0+tm*8+i)*HCd + n0+tn*8+j]=acc[i][j];
}

// X[m][n] = emb[tok[m+tshift]] · Wih_row(n) + b1[n]+b2[n]   (N=4096, K=1024)
__global__ __launch_bounds__(256) void k_xgemm(
    const float* __restrict__ emb, const float* __restrict__ Wih,
    const float* __restrict__ b1, const float* __restrict__ b2,
    const int* __restrict__ tok, int tshift, int M,
    float* __restrict__ X)
{
  __shared__ float As[GBK][GBM];
  __shared__ float Bs[GBK][GBN];
  int tid=threadIdx.x;
  int m0=blockIdx.x*GBM, n0=blockIdx.y*GBN;
  int tm=tid>>4, tn=tid&15;
  int arow=m0+(tid>>1);
  int atok=(arow<M)?tok[arow+tshift]:0;
  const float* abase=emb+(size_t)atok*HCd+(tid&1)*8;
  const float* bbase=Wih+(size_t)(n0+(tid>>1))*HCd+(tid&1)*8;
  int srow=tid>>1;
  float acc[8][8]={};
  for(int k0=0;k0<HCd;k0+=GBK){
#pragma unroll
    for(int u=0;u<2;u++){
      int q=2*(tid&1)+u;
      float4 v={0,0,0,0};
      if(arow<M) v=*(const float4*)(abase+k0+u*4);
      As[q*4+0][srow]=v.x; As[q*4+1][srow]=v.y; As[q*4+2][srow]=v.z; As[q*4+3][srow]=v.w;
      float4 w=*(const float4*)(bbase+k0+u*4);
      Bs[q*4+0][srow]=w.x; Bs[q*4+1][srow]=w.y; Bs[q*4+2][srow]=w.z; Bs[q*4+3][srow]=w.w;
    }
    __syncthreads();
#pragma unroll
    for(int kk=0;kk<GBK;kk++){
      float a[8],b[8];
      *(float4*)&a[0]=*(float4*)&As[kk][tm*8]; *(float4*)&a[4]=*(float4*)&As[kk][tm*8+4];
      *(float4*)&b[0]=*(float4*)&Bs[kk][tn*8]; *(float4*)&b[4]=*(float4*)&Bs[kk][tn*8+4];
#pragma unroll
      for(int i=0;i<8;i++)
#pragma unroll
        for(int j=0;j<8;j++) acc[i][j]+=a[i]*b[j];
    }
    __syncthreads();
  }
#pragma unroll
  for(int i=0;i<8;i++){
    int m=m0+tm*8+i; if(m>=M) continue;
#pragma unroll
    for(int j=0;j<8;j++){
      int n=n0+tn*8+j;
      X[(size_t)m*G4+n]=acc[i][j]+b1[n]+b2[n];
    }
  }
}

// ---------------- Encoder persistent scan (seqlock-LSB protocol) ----------------
__global__ __launch_bounds__(ET,2) void k_enc3(
    const float* __restrict__ Xg,     // [NSE][4096], bias folded in
    const float* __restrict__ Whh,    // [4096][1024]
    unsigned* ehb,                    // [2][1024] state (fp32 bits, LSB=parity)
    float* hT, float* cT)
{
  __shared__ float hlds[2][HCd];
  const int tid=threadIdx.x, lane=tid&63, wv=tid>>6;
  const int wid=blockIdx.x*8+wv;
  const int j0=wid*2, j1=j0+1;
  float w[8][16];
#pragma unroll
  for(int q=0;q<4;q++)
#pragma unroll
    for(int jj=0;jj<2;jj++){
      const float* p=Whh+(size_t)(q*HCd+j0+jj)*HCd+lane;
#pragma unroll
      for(int e=0;e<16;e++) w[q*2+jj][e]=p[(size_t)e*64];
    }
  float xg[8];
#pragma unroll
  for(int r=0;r<8;r++) xg[r]=Xg[(r>>1)*HCd+j0+(r&1)];
  float c0=0.f,c1=0.f;
  const int i0=tid*2, i1=i0+1;

  for(int s=1;s<=NSE;s++){
    unsigned a,b;
    if(s==1){ a=ehb[i0]; b=ehb[i1]; }           // S_0 from prior kernel
    else{
      const unsigned expp=(unsigned)(((s-1)>>1)&1);
      unsigned* src=ehb+((s-1)&1)*HCd;
      for(;;){
        a=__hip_atomic_load(src+i0,__ATOMIC_RELAXED,__HIP_MEMORY_SCOPE_AGENT);
        b=__hip_atomic_load(src+i1,__ATOMIC_RELAXED,__HIP_MEMORY_SCOPE_AGENT);
        if((((a^expp)|(b^expp))&1u)==0u) break;
        __builtin_amdgcn_s_sleep(1);
      }
    }
    float* hl=hlds[(s-1)&1];
    hl[i0]=__uint_as_float(a); hl[i1]=__uint_as_float(b);
    __syncthreads();
    if(s==1){ c0=hl[j0]; c1=hl[j1]; }           // h0 == c0
    float hseg[16];
#pragma unroll
    for(int e=0;e<16;e++) hseg[e]=hl[lane+64*e];
    float d[8];
#pragma unroll
    for(int r=0;r<8;r++){ float sacc=0.f;
#pragma unroll
      for(int e=0;e<16;e++) sacc+=w[r][e]*hseg[e];
      d[r]=sacc; }
#pragma unroll
    for(int r=0;r<8;r++) d[r]=wave_reduce(d[r]);
    float gi0=d[0]+xg[0], gi1=d[1]+xg[1];
    float gf0=d[2]+xg[2], gf1=d[3]+xg[3];
    float gg0=d[4]+xg[4], gg1=d[5]+xg[5];
    float go0=d[6]+xg[6], go1=d[7]+xg[7];
    if(s<NSE){
      const float* px=Xg+(size_t)s*G4;
#pragma unroll
      for(int r=0;r<8;r++) xg[r]=px[(r>>1)*HCd+j0+(r&1)];
    }
    c0=sigmoidf_(gf0)*c0+sigmoidf_(gi0)*tanhf(gg0);
    float h0=sigmoidf_(go0)*tanhf(c0);
    c1=sigmoidf_(gf1)*c1+sigmoidf_(gi1)*tanhf(gg1);
    float h1=sigmoidf_(go1)*tanhf(c1);
    unsigned wpar=(unsigned)((s>>1)&1);
    if(lane==0){
      unsigned* dst=ehb+(s&1)*HCd;
      __hip_atomic_store(dst+j0,(__float_as_uint(h0)&~1u)|wpar,__ATOMIC_RELAXED,__HIP_MEMORY_SCOPE_AGENT);
      __hip_atomic_store(dst+j1,(__float_as_uint(h1)&~1u)|wpar,__ATOMIC_RELAXED,__HIP_MEMORY_SCOPE_AGENT);
      if(s==NSE){ hT[j0]=h0; hT[j1]=h1; cT[j0]=c0; cT[j1]=c1; }
    }
  }
}

// ---------------- VAE heads ----------------
__global__ __launch_bounds__(256) void k_head(
    const float* __restrict__ hT, const float* __restrict__ cT,
    const float* __restrict__ mhw, const float* __restrict__ mhb,
    const float* __restrict__ lhw, const float* __restrict__ lhb,
    const float* __restrict__ mcw, const float* __restrict__ mcb,
    const float* __restrict__ lcw, const float* __restrict__ lcb,
    const float* __restrict__ eps_h, const float* __restrict__ eps_c,
    const float* __restrict__ cemb, const int* __restrict__ condp,
    unsigned* dh0, unsigned* dc0, float* klh, float* klc)
{
  int i=blockIdx.x;
  int tid=threadIdx.x, lane=tid&63, wv=tid>>6;
  __shared__ float sm[4];
  const float* Wm=(wv==0)?mhw:(wv==1)?lhw:(wv==2)?mcw:lcw;
  const float* vec=(wv<2)?hT:cT;
  const float* row=Wm+(size_t)i*HCd;
  float s=0.f;
  for(int k=lane;k<HCd;k+=64) s+=row[k]*vec[k];
  s=wave_reduce(s);
  if(lane==0) sm[wv]=s;
  __syncthreads();
  if(tid==0){
    float mh=sm[0]+mhb[i], lh=sm[1]+lhb[i];
    float mc=sm[2]+mcb[i], lc=sm[3]+lcb[i];
    float zhv=eps_h[i]*expf(lh*0.5f)+mh;
    float zcv=eps_c[i]*expf(lc*0.5f)+mc;
    dh0[i]=__float_as_uint(zhv)&~1u;     // S_0, parity 0
    dc0[i]=__float_as_uint(zcv)&~1u;
    klh[i]=0.5f*(mh*mh+expf(lh)-1.f-lh);
    klc[i]=0.5f*(mc*mc+expf(lc)-1.f-lc);
    if(i<Cc){
      unsigned cu=__float_as_uint(cemb[condp[0]*Cc+i])&~1u;
      dh0[Hh+i]=cu; dc0[Hh+i]=cu;
    }
  }
}

// decoder step 1: gates = Xdec[0] + WhhO·S0.h; cc = S0.c[j]; writes S_1 (parity 0)
__global__ __launch_bounds__(256) void k_dec0(
    const float* __restrict__ Xg, const float* __restrict__ WhhO,
    const unsigned* __restrict__ dh0, const unsigned* __restrict__ dc0,
    unsigned* dh1, unsigned* dc1, float* Hmat)
{
  int tid=threadIdx.x, lane=tid&63, wv=tid>>6;
  int j=blockIdx.x*4+wv;
  float hseg[16];
#pragma unroll
  for(int e=0;e<16;e++) hseg[e]=__uint_as_float(dh0[lane+64*e]);
  float g[4];
#pragma unroll
  for(int q=0;q<4;q++){
    const float* p=WhhO+(size_t)(q*HCd+j)*HCd+lane;
    float s=0.f;
#pragma unroll
    for(int e=0;e<16;e++) s+=p[(size_t)e*64]*hseg[e];
    s=wave_reduce(s);
    g[q]=s+Xg[q*HCd+j];
  }
  float cc=__uint_as_float(dc0[j]);
  float cn=sigmoidf_(g[1])*cc+sigmoidf_(g[0])*tanhf(g[2]);
  float hn=sigmoidf_(g[3])*tanhf(cn);
  if(lane==0){
    dh1[j]=__float_as_uint(hn)&~1u;
    dc1[j]=__float_as_uint(cn)&~1u;
    Hmat[j]=hn;
  }
}

// ---------------- Decoder persistent scan (s = 2..NSD, seqlock-LSB) ----------------
__global__ __launch_bounds__(ET,2) void k_dec3(
    const float* __restrict__ Xg,     // [NSD][4096], bias folded
    const float* __restrict__ Weff,
    const float* __restrict__ cvec,
    const float* __restrict__ fccw, const float* __restrict__ fccb,
    const float* __restrict__ cemb, const int* __restrict__ condp,
    unsigned* dhb, unsigned* dcb, float* __restrict__ Hmat)
{
  __shared__ float hlds[2][HCd];
  __shared__ float clds[2][HCd];
  const int tid=threadIdx.x, lane=tid&63, wv=tid>>6;
  const int wid=blockIdx.x*8+wv;
  const int j0=wid*2, j1=j0+1;
  float w[8][16];
#pragma unroll
  for(int q=0;q<4;q++)
#pragma unroll
    for(int jj=0;jj<2;jj++){
      const float* p=Weff+(size_t)(q*HCd+j0+jj)*HCd+lane;
#pragma unroll
      for(int e=0;e<16;e++) w[q*2+jj][e]=p[(size_t)e*64];
    }
  const bool hasf=(j0<Hh);
  float fcc0[16], fcc1[16];
  if(hasf){
    const float* p0=fccw+(size_t)j0*HCd+lane;
    const float* p1=fccw+(size_t)j1*HCd+lane;
#pragma unroll
    for(int e=0;e<16;e++){ fcc0[e]=p0[(size_t)e*64]; fcc1[e]=p1[(size_t)e*64]; }
  } else {
#pragma unroll
    for(int e=0;e<16;e++){ fcc0[e]=0.f; fcc1[e]=0.f; }
  }
  float fb0=hasf?fccb[j0]:0.f, fb1=hasf?fccb[j1]:0.f;
  int cond=condp[0];
  float cd0=hasf?0.f:cemb[cond*Cc+(j0-Hh)];
  float cd1=hasf?0.f:cemb[cond*Cc+(j1-Hh)];
  float cv[8];
#pragma unroll
  for(int r=0;r<8;r++) cv[r]=cvec[(r>>1)*HCd+j0+(r&1)];
  float xg[8];
  { const float* px=Xg+(size_t)1*G4;
#pragma unroll
    for(int r=0;r<8;r++) xg[r]=px[(r>>1)*HCd+j0+(r&1)]; }
  const int i0=tid*2, i1=i0+1;

  for(int s=2;s<=NSD;s++){
    unsigned a,b,e2,f2;
    unsigned* sh=dhb+((s-1)&1)*HCd;
    unsigned* sc=dcb+((s-1)&1)*HCd;
    if(s==2){ a=sh[i0]; b=sh[i1]; e2=sc[i0]; f2=sc[i1]; }   // S_1 from k_dec0
    else{
      const unsigned expp=(unsigned)(((s-1)>>1)&1);
      for(;;){
        a =__hip_atomic_load(sh+i0,__ATOMIC_RELAXED,__HIP_MEMORY_SCOPE_AGENT);
        b =__hip_atomic_load(sh+i1,__ATOMIC_RELAXED,__HIP_MEMORY_SCOPE_AGENT);
        e2=__hip_atomic_load(sc+i0,__ATOMIC_RELAXED,__HIP_MEMORY_SCOPE_AGENT);
        f2=__hip_atomic_load(sc+i1,__ATOMIC_RELAXED,__HIP_MEMORY_SCOPE_AGENT);
        if((((a^expp)|(b^expp)|(e2^expp)|(f2^expp))&1u)==0u) break;
        __builtin_amdgcn_s_sleep(1);
      }
    }
    float* hl=hlds[(s-1)&1]; float* cl=clds[(s-1)&1];
    hl[i0]=__uint_as_float(a);  hl[i1]=__uint_as_float(b);
    cl[i0]=__uint_as_float(e2); cl[i1]=__uint_as_float(f2);
    __syncthreads();
    float hseg[16], cseg[16];
#pragma unroll
    for(int e=0;e<16;e++){ hseg[e]=hl[lane+64*e]; cseg[e]=cl[lane+64*e]; }
    float d[8]; float s8=0.f, s9=0.f;
#pragma unroll
    for(int r=0;r<8;r++){ float sacc=0.f;
#pragma unroll
      for(int e=0;e<16;e++) sacc+=w[r][e]*hseg[e];
      d[r]=sacc; }
    if(hasf){
#pragma unroll
      for(int e=0;e<16;e++){ s8+=fcc0[e]*cseg[e]; s9+=fcc1[e]*cseg[e]; }
    }
#pragma unroll
    for(int r=0;r<8;r++) d[r]=wave_reduce(d[r]);
    s8=wave_reduce(s8); s9=wave_reduce(s9);
    float gi0=d[0]+xg[0]+cv[0], gi1=d[1]+xg[1]+cv[1];
    float gf0=d[2]+xg[2]+cv[2], gf1=d[3]+xg[3]+cv[3];
    float gg0=d[4]+xg[4]+cv[4], gg1=d[5]+xg[5]+cv[5];
    float go0=d[6]+xg[6]+cv[6], go1=d[7]+xg[7]+cv[7];
    if(s<NSD){
      const float* px=Xg+(size_t)s*G4;
#pragma unroll
      for(int r=0;r<8;r++) xg[r]=px[(r>>1)*HCd+j0+(r&1)];
    }
    float cc0=hasf?(s8+fb0):cd0;
    float cc1=hasf?(s9+fb1):cd1;
    float cn0=sigmoidf_(gf0)*cc0+sigmoidf_(gi0)*tanhf(gg0);
    float hn0=sigmoidf_(go0)*tanhf(cn0);
    float cn1=sigmoidf_(gf1)*cc1+sigmoidf_(gi1)*tanhf(gg1);
    float hn1=sigmoidf_(go1)*tanhf(cn1);
    unsigned wpar=(unsigned)((s>>1)&1);
    if(lane==0){
      unsigned* wh=dhb+(s&1)*HCd;
      unsigned* wc=dcb+(s&1)*HCd;
      __hip_atomic_store(wh+j0,(__float_as_uint(hn0)&~1u)|wpar,__ATOMIC_RELAXED,__HIP_MEMORY_SCOPE_AGENT);
      __hip_atomic_store(wh+j1,(__float_as_uint(hn1)&~1u)|wpar,__ATOMIC_RELAXED,__HIP_MEMORY_SCOPE_AGENT);
      __hip_atomic_store(wc+j0,(__float_as_uint(cn0)&~1u)|wpar,__ATOMIC_RELAXED,__HIP_MEMORY_SCOPE_AGENT);
      __hip_atomic_store(wc+j1,(__float_as_uint(cn1)&~1u)|wpar,__ATOMIC_RELAXED,__HIP_MEMORY_SCOPE_AGENT);
      Hmat[(size_t)(s-1)*HCd+j0]=hn0; Hmat[(size_t)(s-1)*HCd+j1]=hn1;
    }
  }
}

// ---------------- logits GEMM (C = A·B^T + bias) ----------------
__global__ __launch_bounds__(256) void k_gemm_tn_bias(
    const float* __restrict__ A, const float* __restrict__ B,
    const float* __restrict__ bias, float* __restrict__ Cm, int M)
{
  __shared__ float As[GBK][GBM];
  __shared__ float Bs[GBK][GBN];
  int tid=threadIdx.x;
  int m0=blockIdx.x*GBM, n0=blockIdx.y*GBN;
  int tm=tid>>4, tn=tid&15;
  float acc[8][8]={};
  for(int k0=0;k0<HCd;k0+=GBK){
#pragma unroll
    for(int u=0;u<2;u++){
      int idx=tid*2+u; int row=idx>>2, q=idx&3;
      float4 v={0,0,0,0};
      if(m0+row<M) v=*(const float4*)(A+(size_t)(m0+row)*HCd + k0+q*4);
      As[q*4+0][row]=v.x; As[q*4+1][row]=v.y; As[q*4+2][row]=v.z; As[q*4+3][row]=v.w;
      float4 w=*(const float4*)(B+(size_t)(n0+row)*HCd + k0+q*4);
      Bs[q*4+0][row]=w.x; Bs[q*4+1][row]=w.y; Bs[q*4+2][row]=w.z; Bs[q*4+3][row]=w.w;
    }
    __syncthreads();
#pragma unroll
    for(int kk=0;kk<GBK;kk++){
      float a[8],b[8];
      *(float4*)&a[0]=*(float4*)&As[kk][tm*8]; *(float4*)&a[4]=*(float4*)&As[kk][tm*8+4];
      *(float4*)&b[0]=*(float4*)&Bs[kk][tn*8]; *(float4*)&b[4]=*(float4*)&Bs[kk][tn*8+4];
#pragma unroll
      for(int i=0;i<8;i++)
#pragma unroll
        for(int j=0;j<8;j++) acc[i][j]+=a[i]*b[j];
    }
    __syncthreads();
  }
#pragma unroll
  for(int i=0;i<8;i++){
    int m=m0+tm*8+i; if(m>=M) continue;
#pragma unroll
    for(int j=0;j<8;j++){
      int n=n0+tn*8+j;
      Cm[(size_t)m*VSZ+n]=acc[i][j]+bias[n];
    }
  }
}

// per-row cross-entropy
__global__ __launch_bounds__(256) void k_ce(const float* __restrict__ logits,
    const int* __restrict__ tok, int base, float* __restrict__ ce)
{
  int r=blockIdx.x;
  const float* row=logits+(size_t)r*VSZ;
  int tid=threadIdx.x, lane=tid&63, wv=tid>>6;
  __shared__ float sm1[4];
  __shared__ float sm2[4];
  float m=-1e30f;
  for(int i=tid;i<VSZ;i+=256) m=fmaxf(m,row[i]);
#pragma unroll
  for(int o=32;o;o>>=1) m=fmaxf(m,__shfl_xor(m,o,64));
  if(lane==0) sm1[wv]=m;
  __syncthreads();
  m=fmaxf(fmaxf(sm1[0],sm1[1]),fmaxf(sm1[2],sm1[3]));
  float s=0.f;
  for(int i=tid;i<VSZ;i+=256) s+=__expf(row[i]-m);
  s=wave_reduce(s);
  if(lane==0) sm2[wv]=s;
  __syncthreads();
  if(tid==0){
    float tot=sm2[0]+sm2[1]+sm2[2]+sm2[3];
    int tgt=tok[base+r+1];
    ce[base+r]=m+logf(tot)-row[tgt];
  }
}

__global__ __launch_bounds__(256) void k_final(const float* __restrict__ ce,
    const float* __restrict__ klh, const float* __restrict__ klc,
    const float* __restrict__ kldw, float* __restrict__ outp)
{
  int tid=threadIdx.x, lane=tid&63, wv=tid>>6;
  float s0=0,s1=0,s2=0;
  for(int i=tid;i<NSD;i+=256) s0+=ce[i];
  for(int i=tid;i<Hh;i+=256){ s1+=klh[i]; s2+=klc[i]; }
  s0=wave_reduce(s0); s1=wave_reduce(s1); s2=wave_reduce(s2);
  __shared__ float sm[3][4];
  if(lane==0){ sm[0][wv]=s0; sm[1][wv]=s1; sm[2][wv]=s2; }
  __syncthreads();
  if(tid==0){
    float ces=sm[0][0]+sm[0][1]+sm[0][2]+sm[0][3];
    float kh =sm[1][0]+sm[1][1]+sm[1][2]+sm[1][3];
    float kc =sm[2][0]+sm[2][1]+sm[2][2]+sm[2][3];
    float rec=ces/(float)NSD;
    outp[0]=rec+(kh+kc)*kldw[0];
    outp[1]=rec; outp[2]=kh; outp[3]=kc;
  }
}

extern "C" void kernel_launch(void* const* d_in, const int* in_sizes, int n_in,
                              void* d_out, int out_size, void* d_ws, size_t ws_size,
                              hipStream_t stream) {
  const int*   tok   =(const int*)  d_in[0];
  const int*   cond  =(const int*)  d_in[1];
  const float* eps_h =(const float*)d_in[2];
  const float* eps_c =(const float*)d_in[3];
  const float* kldw  =(const float*)d_in[4];
  const float* enc_embed=(const float*)d_in[5];
  const float* enc_cemb =(const float*)d_in[6];
  const float* enc_Wih  =(const float*)d_in[7];
  const float* enc_Whh  =(const float*)d_in[8];
  const float* enc_bih  =(const float*)d_in[9];
  const float* enc_bhh  =(const float*)d_in[10];
  const float* fc_mh_w=(const float*)d_in[11];
  const float* fc_mh_b=(const float*)d_in[12];
  const float* fc_lh_w=(const float*)d_in[13];
  const float* fc_lh_b=(const float*)d_in[14];
  const float* fc_mc_w=(const float*)d_in[15];
  const float* fc_mc_b=(const float*)d_in[16];
  const float* fc_lc_w=(const float*)d_in[17];
  const float* fc_lc_b=(const float*)d_in[18];
  const float* dec_embed=(const float*)d_in[19];
  const float* dec_cemb =(const float*)d_in[20];
  const float* dec_Wih  =(const float*)d_in[21];
  const float* dec_Whh  =(const float*)d_in[22];
  const float* dec_bih  =(const float*)d_in[23];
  const float* dec_bhh  =(const float*)d_in[24];
  const float* fc_h_w=(const float*)d_in[25];
  const float* fc_h_b=(const float*)d_in[26];
  const float* fc_c_w=(const float*)d_in[27];
  const float* fc_c_b=(const float*)d_in[28];
  const float* out_w=(const float*)d_in[29];
  const float* out_b=(const float*)d_in[30];

  float* ws=(float*)d_ws;
  size_t off=0;
  unsigned* ehb=(unsigned*)(ws+off); off+=2*HCd;
  unsigned* dhb=(unsigned*)(ws+off); off+=2*HCd;
  unsigned* dcb=(unsigned*)(ws+off); off+=2*HCd;
  float* cvec=ws+off; off+=G4;
  float* Weff=ws+off; off+=(size_t)G4*HCd;
  float* hT  =ws+off; off+=HCd;
  float* cT  =ws+off; off+=HCd;
  float* klh =ws+off; off+=Hh;
  float* klc =ws+off; off+=Hh;
  float* Hmat=ws+off; off+=(size_t)NSD*HCd;
  float* ce  =ws+off; off+=2048;
  float* X   =ws+off;                       // shared region: Xenc / Xdec / lbuf
  size_t avail=ws_size/4;
  size_t region=(avail>off)?(avail-off):0;
  int chunk=256;
  if((size_t)chunk*VSZ>region){
    chunk=(int)(region/(size_t)VSZ);
    if(chunk<1) chunk=1;
  }
  float* lbuf=X;

  k_init3<<<1,256,0,stream>>>(ehb,enc_cemb,cond);
  k_dconst<<<64,256,0,stream>>>(dec_Whh,fc_h_b,dec_cemb,cond,cvec);
  { dim3 g(G4/GBM, HCd/GBN);
    k_weff<<<g,256,0,stream>>>(dec_Whh,fc_h_w,Weff); }
  { dim3 g((NSE+GBM-1)/GBM, G4/GBN);        // Xenc
    k_xgemm<<<g,256,0,stream>>>(enc_embed,enc_Wih,enc_bih,enc_bhh,tok,1,NSE,X); }
  k_enc3<<<EB,ET,0,stream>>>(X,enc_Whh,ehb,hT,cT);
  k_head<<<Hh,256,0,stream>>>(hT,cT,fc_mh_w,fc_mh_b,fc_lh_w,fc_lh_b,
                              fc_mc_w,fc_mc_b,fc_lc_w,fc_lc_b,
                              eps_h,eps_c,dec_cemb,cond,dhb,dcb,klh,klc);
  { dim3 g((NSD+GBM-1)/GBM, G4/GBN);        // Xdec (overwrites Xenc — encoder done)
    k_xgemm<<<g,256,0,stream>>>(dec_embed,dec_Wih,dec_bih,dec_bhh,tok,0,NSD,X); }
  k_dec0<<<256,256,0,stream>>>(X,dec_Whh,dhb,dcb,dhb+HCd,dcb+HCd,Hmat);
  k_dec3<<<EB,ET,0,stream>>>(X,Weff,cvec,fc_c_w,fc_c_b,dec_cemb,cond,dhb,dcb,Hmat);
  for(int base=0;base<NSD;base+=chunk){     // lbuf overlays X — decoder done
    int rows=NSD-base; if(rows>chunk) rows=chunk;
    dim3 g((rows+GBM-1)/GBM, VSZ/GBN);
    k_gemm_tn_bias<<<g,256,0,stream>>>(Hmat+(size_t)base*HCd,out_w,out_b,lbuf,rows);
    k_ce<<<rows,256,0,stream>>>(lbuf,tok,base,ce);
  }
  k_final<<<1,256,0,stream>>>(ce,klh,klc,kldw,(float*)d_out);
}

// Round 4
// 17703.635 us; speedup vs baseline: 5.2406x; 1.3063x over previous
//
#include <hip/hip_runtime.h>
#include <math.h>

// Problem sizes (fixed)
#define VSZ 32000
#define Hh  768
#define Cc  256
#define HCd 1024
#define G4  4096
#define NSE 2046   // encoder steps
#define NSD 2047   // decoder steps

// Persistent scan shape: 64 blocks x 512 threads (8 waves) = 512 waves,
// each wave owns 2 output elements (8 gate rows).
#define EB 64
#define ET 512

typedef __attribute__((ext_vector_type(4))) unsigned uint4v;
typedef __attribute__((ext_vector_type(2))) unsigned uint2v;
typedef __attribute__((ext_vector_type(8))) short bf16x8;
typedef __attribute__((ext_vector_type(4))) float f32x4;

__device__ __forceinline__ float sigmoidf_(float x){ return 1.0f/(1.0f+expf(-x)); }

__device__ __forceinline__ float wave_reduce(float v){
#pragma unroll
  for(int o=32;o;o>>=1) v += __shfl_xor(v,o,64);
  return v;
}

// Uncached (coherence-point) vector load/store: single transaction for the
// whole per-thread state slice. Per-dword LSB parity makes each dword
// self-validating, so no multi-word atomicity is required.
__device__ __forceinline__ uint4v ld_uc4(const unsigned* p){
  uint4v r;
  asm volatile("global_load_dwordx4 %0, %1, off sc0 sc1\n\ts_waitcnt vmcnt(0)"
               : "=v"(r) : "v"(p) : "memory");
  return r;
}
__device__ __forceinline__ uint2v ld_uc2(const unsigned* p){
  uint2v r;
  asm volatile("global_load_dwordx2 %0, %1, off sc0 sc1\n\ts_waitcnt vmcnt(0)"
               : "=v"(r) : "v"(p) : "memory");
  return r;
}
__device__ __forceinline__ void st_uc4(unsigned* p, uint4v v){
  asm volatile("global_store_dwordx4 %0, %1, off sc0 sc1" :: "v"(p), "v"(v) : "memory");
}
__device__ __forceinline__ void st_uc2(unsigned* p, uint2v v){
  asm volatile("global_store_dwordx2 %0, %1, off sc0 sc1" :: "v"(p), "v"(v) : "memory");
}

// round-to-nearest-even fp32->bf16, pack two into a dword
__device__ __forceinline__ unsigned pk_bf16(float a, float b){
  unsigned ua=__float_as_uint(a); ua += 0x7fffu + ((ua>>16)&1u);
  unsigned ub=__float_as_uint(b); ub += 0x7fffu + ((ub>>16)&1u);
  return (ua>>16) | (ub & 0xffff0000u);
}

// init: encoder S_0 into estate slot0 (parity 0), slot1 poisoned to parity 1
__global__ void k_init3(unsigned* estate, const float* __restrict__ cemb,
                        const int* __restrict__ condp){
  int tid=threadIdx.x;
  int cond=condp[0];
  for(int i=tid;i<HCd;i+=256){
    float v=(i<Hh)?0.f:cemb[cond*Cc+(i-Hh)];
    estate[i]=__float_as_uint(v)&~1u;   // S_0, parity 0
    estate[HCd+i]=1u;                   // stale slot: parity 1
  }
}

// dec_const[r] = dec_W_hh[r,0:768]·fc_h_b + dec_W_hh[r,768:1024]·cd
__global__ __launch_bounds__(256) void k_dconst(const float* __restrict__ Whh,
    const float* __restrict__ fhb, const float* __restrict__ cemb,
    const int* __restrict__ condp, float* __restrict__ cvec){
  int lane=threadIdx.x&63, wv=threadIdx.x>>6;
  int wgid=blockIdx.x*4+wv;
  int cond=condp[0];
  for(int r=wgid;r<G4;r+=256){
    const float* row=Whh+(size_t)r*HCd;
    float s=0.f;
    for(int k=lane;k<Hh;k+=64) s+=row[k]*fhb[k];
    for(int k=lane;k<Cc;k+=64) s+=row[Hh+k]*cemb[cond*Cc+k];
    s=wave_reduce(s);
    if(lane==0) cvec[r]=s;
  }
}

#define GBM 128
#define GBN 128
#define GBK 16

// Weff[r,k] = sum_{i<768} dec_W_hh[r,i]*fc_h_w[i,k]   (M=4096,N=1024,K=768)
__global__ __launch_bounds__(256) void k_weff(const float* __restrict__ A,
    const float* __restrict__ B, float* __restrict__ Cm){
  __shared__ float As[GBK][GBM];
  __shared__ float Bs[GBK][GBN];
  int tid=threadIdx.x;
  int m0=blockIdx.x*GBM, n0=blockIdx.y*GBN;
  int tm=tid>>4, tn=tid&15;
  float acc[8][8]={};
  for(int k0=0;k0<Hh;k0+=GBK){
#pragma unroll
    for(int u=0;u<2;u++){
      int idx=tid*2+u;
      int row=idx>>2, q=idx&3;
      float4 v=*(const float4*)(A+(size_t)(m0+row)*HCd + k0+q*4);
      As[q*4+0][row]=v.x; As[q*4+1][row]=v.y; As[q*4+2][row]=v.z; As[q*4+3][row]=v.w;
      int kk=idx>>5, nc=idx&31;
      float4 w=*(const float4*)(B+(size_t)(k0+kk)*HCd + n0+nc*4);
      *(float4*)&Bs[kk][nc*4]=w;
    }
    __syncthreads();
#pragma unroll
    for(int kk=0;kk<GBK;kk++){
      float a[8],b[8];
      *(float4*)&a[0]=*(float4*)&As[kk][tm*8]; *(float4*)&a[4]=*(float4*)&As[kk][tm*8+4];
      *(float4*)&b[0]=*(float4*)&Bs[kk][tn*8]; *(float4*)&b[4]=*(float4*)&Bs[kk][tn*8+4];
#pragma unroll
      for(int i=0;i<8;i++)
#pragma unroll
        for(int j=0;j<8;j++) acc[i][j]+=a[i]*b[j];
    }
    __syncthreads();
  }
#pragma unroll
  for(int i=0;i<8;i++)
#pragma unroll
    for(int j=0;j<8;j++)
      Cm[(size_t)(m0+tm*8+i)*HCd + n0+tn*8+j]=acc[i][j];
}

// X[m][n] = emb[tok[m+tshift]] · Wih_row(n) + b1[n]+b2[n]   (N=4096, K=1024)
__global__ __launch_bounds__(256) void k_xgemm(
    const float* __restrict__ emb, const float* __restrict__ Wih,
    const float* __restrict__ b1, const float* __restrict__ b2,
    const int* __restrict__ tok, int tshift, int M,
    float* __restrict__ X)
{
  __shared__ float As[GBK][GBM];
  __shared__ float Bs[GBK][GBN];
  int tid=threadIdx.x;
  int m0=blockIdx.x*GBM, n0=blockIdx.y*GBN;
  int tm=tid>>4, tn=tid&15;
  int arow=m0+(tid>>1);
  int atok=(arow<M)?tok[arow+tshift]:0;
  const float* abase=emb+(size_t)atok*HCd+(tid&1)*8;
  const float* bbase=Wih+(size_t)(n0+(tid>>1))*HCd+(tid&1)*8;
  int srow=tid>>1;
  float acc[8][8]={};
  for(int k0=0;k0<HCd;k0+=GBK){
#pragma unroll
    for(int u=0;u<2;u++){
      int q=2*(tid&1)+u;
      float4 v={0,0,0,0};
      if(arow<M) v=*(const float4*)(abase+k0+u*4);
      As[q*4+0][srow]=v.x; As[q*4+1][srow]=v.y; As[q*4+2][srow]=v.z; As[q*4+3][srow]=v.w;
      float4 w=*(const float4*)(bbase+k0+u*4);
      Bs[q*4+0][srow]=w.x; Bs[q*4+1][srow]=w.y; Bs[q*4+2][srow]=w.z; Bs[q*4+3][srow]=w.w;
    }
    __syncthreads();
#pragma unroll
    for(int kk=0;kk<GBK;kk++){
      float a[8],b[8];
      *(float4*)&a[0]=*(float4*)&As[kk][tm*8]; *(float4*)&a[4]=*(float4*)&As[kk][tm*8+4];
      *(float4*)&b[0]=*(float4*)&Bs[kk][tn*8]; *(float4*)&b[4]=*(float4*)&Bs[kk][tn*8+4];
#pragma unroll
      for(int i=0;i<8;i++)
#pragma unroll
        for(int j=0;j<8;j++) acc[i][j]+=a[i]*b[j];
    }
    __syncthreads();
  }
#pragma unroll
  for(int i=0;i<8;i++){
    int m=m0+tm*8+i; if(m>=M) continue;
#pragma unroll
    for(int j=0;j<8;j++){
      int n=n0+tn*8+j;
      X[(size_t)m*G4+n]=acc[i][j]+b1[n]+b2[n];
    }
  }
}

// ---------------- Encoder persistent scan (seqlock-LSB, 1 uncached ld/step) ----------------
__global__ __launch_bounds__(ET,2) void k_enc3(
    const float* __restrict__ Xg,     // [NSE][4096], bias folded in
    const float* __restrict__ Whh,    // [4096][1024]
    unsigned* estate,                 // [2][1024] h (fp32 bits, LSB=parity)
    float* hT, float* cT)
{
  __shared__ float hlds[2][HCd];
  const int tid=threadIdx.x, lane=tid&63, wv=tid>>6;
  const int wid=blockIdx.x*8+wv;
  const int j0=wid*2, j1=j0+1;
  float w[8][16];
#pragma unroll
  for(int q=0;q<4;q++)
#pragma unroll
    for(int jj=0;jj<2;jj++){
      const float* p=Whh+(size_t)(q*HCd+j0+jj)*HCd+lane;
#pragma unroll
      for(int e=0;e<16;e++) w[q*2+jj][e]=p[(size_t)e*64];
    }
  float xg[8];
#pragma unroll
  for(int r=0;r<8;r++) xg[r]=Xg[(r>>1)*HCd+j0+(r&1)];
  float c0=0.f,c1=0.f;
  const int i0=tid*2, i1=i0+1;

  for(int s=1;s<=NSE;s++){
    uint2v v;
    unsigned* src=estate+((s-1)&1)*HCd;
    if(s==1){ v.x=src[i0]; v.y=src[i1]; }       // S_0 from prior kernel
    else{
      const unsigned expp=(unsigned)(((s-1)>>1)&1);
      for(;;){
        v=ld_uc2(src+i0);
        if((((v.x^expp)|(v.y^expp))&1u)==0u) break;
        __builtin_amdgcn_s_sleep(1);
      }
    }
    float* hl=hlds[(s-1)&1];
    hl[i0]=__uint_as_float(v.x); hl[i1]=__uint_as_float(v.y);
    __syncthreads();
    if(s==1){ c0=hl[j0]; c1=hl[j1]; }           // h0 == c0
    float hseg[16];
#pragma unroll
    for(int e=0;e<16;e++) hseg[e]=hl[lane+64*e];
    float d[8];
#pragma unroll
    for(int r=0;r<8;r++){ float sacc=0.f;
#pragma unroll
      for(int e=0;e<16;e++) sacc+=w[r][e]*hseg[e];
      d[r]=sacc; }
#pragma unroll
    for(int r=0;r<8;r++) d[r]=wave_reduce(d[r]);
    float gi0=d[0]+xg[0], gi1=d[1]+xg[1];
    float gf0=d[2]+xg[2], gf1=d[3]+xg[3];
    float gg0=d[4]+xg[4], gg1=d[5]+xg[5];
    float go0=d[6]+xg[6], go1=d[7]+xg[7];
    if(s<NSE){
      const float* px=Xg+(size_t)s*G4;
#pragma unroll
      for(int r=0;r<8;r++) xg[r]=px[(r>>1)*HCd+j0+(r&1)];
    }
    c0=sigmoidf_(gf0)*c0+sigmoidf_(gi0)*tanhf(gg0);
    float h0=sigmoidf_(go0)*tanhf(c0);
    c1=sigmoidf_(gf1)*c1+sigmoidf_(gi1)*tanhf(gg1);
    float h1=sigmoidf_(go1)*tanhf(c1);
    unsigned wpar=(unsigned)((s>>1)&1);
    if(lane==0){
      uint2v pk;
      pk.x=(__float_as_uint(h0)&~1u)|wpar;
      pk.y=(__float_as_uint(h1)&~1u)|wpar;
      st_uc2(estate+(s&1)*HCd+j0,pk);
      if(s==NSE){ hT[j0]=h0; hT[j1]=h1; cT[j0]=c0; cT[j1]=c1; }
    }
  }
}

// ---------------- VAE heads ----------------
// writes decoder S_0 interleaved: dstate0[2j]=h, dstate0[2j+1]=c, parity 0
__global__ __launch_bounds__(256) void k_head(
    const float* __restrict__ hT, const float* __restrict__ cT,
    const float* __restrict__ mhw, const float* __restrict__ mhb,
    const float* __restrict__ lhw, const float* __restrict__ lhb,
    const float* __restrict__ mcw, const float* __restrict__ mcb,
    const float* __restrict__ lcw, const float* __restrict__ lcb,
    const float* __restrict__ eps_h, const float* __restrict__ eps_c,
    const float* __restrict__ cemb, const int* __restrict__ condp,
    unsigned* dstate0, float* klh, float* klc)
{
  int i=blockIdx.x;
  int tid=threadIdx.x, lane=tid&63, wv=tid>>6;
  __shared__ float sm[4];
  const float* Wm=(wv==0)?mhw:(wv==1)?lhw:(wv==2)?mcw:lcw;
  const float* vec=(wv<2)?hT:cT;
  const float* row=Wm+(size_t)i*HCd;
  float s=0.f;
  for(int k=lane;k<HCd;k+=64) s+=row[k]*vec[k];
  s=wave_reduce(s);
  if(lane==0) sm[wv]=s;
  __syncthreads();
  if(tid==0){
    float mh=sm[0]+mhb[i], lh=sm[1]+lhb[i];
    float mc=sm[2]+mcb[i], lc=sm[3]+lcb[i];
    float zhv=eps_h[i]*expf(lh*0.5f)+mh;
    float zcv=eps_c[i]*expf(lc*0.5f)+mc;
    dstate0[2*i]  =__float_as_uint(zhv)&~1u;
    dstate0[2*i+1]=__float_as_uint(zcv)&~1u;
    klh[i]=0.5f*(mh*mh+expf(lh)-1.f-lh);
    klc[i]=0.5f*(mc*mc+expf(lc)-1.f-lc);
    if(i<Cc){
      unsigned cu=__float_as_uint(cemb[condp[0]*Cc+i])&~1u;
      dstate0[2*(Hh+i)]=cu; dstate0[2*(Hh+i)+1]=cu;
    }
  }
}

// decoder step 1: gates = Xdec[0] + WhhO·S0.h; cc = S0.c[j]; writes S_1 (parity 0)
__global__ __launch_bounds__(256) void k_dec0(
    const float* __restrict__ Xg, const float* __restrict__ WhhO,
    const unsigned* __restrict__ dstate0, unsigned* dstate1, float* Hmat)
{
  int tid=threadIdx.x, lane=tid&63, wv=tid>>6;
  int j=blockIdx.x*4+wv;
  float hseg[16];
#pragma unroll
  for(int e=0;e<16;e++) hseg[e]=__uint_as_float(dstate0[2*(lane+64*e)]);
  float g[4];
#pragma unroll
  for(int q=0;q<4;q++){
    const float* p=WhhO+(size_t)(q*HCd+j)*HCd+lane;
    float s=0.f;
#pragma unroll
    for(int e=0;e<16;e++) s+=p[(size_t)e*64]*hseg[e];
    s=wave_reduce(s);
    g[q]=s+Xg[q*HCd+j];
  }
  float cc=__uint_as_float(dstate0[2*j+1]);
  float cn=sigmoidf_(g[1])*cc+sigmoidf_(g[0])*tanhf(g[2]);
  float hn=sigmoidf_(g[3])*tanhf(cn);
  if(lane==0){
    dstate1[2*j]  =__float_as_uint(hn)&~1u;
    dstate1[2*j+1]=__float_as_uint(cn)&~1u;
    Hmat[j]=hn;
  }
}

// ---------------- Decoder persistent scan (s = 2..NSD, 1 uncached ldx4/step) ----------------
__global__ __launch_bounds__(ET,2) void k_dec3(
    const float* __restrict__ Xg,     // [NSD][4096], bias folded
    const float* __restrict__ Weff,
    const float* __restrict__ cvec,
    const float* __restrict__ fccw, const float* __restrict__ fccb,
    const float* __restrict__ cemb, const int* __restrict__ condp,
    unsigned* dstate, float* __restrict__ Hmat)
{
  __shared__ float hlds[2][HCd];
  __shared__ float clds[2][HCd];
  const int tid=threadIdx.x, lane=tid&63, wv=tid>>6;
  const int wid=blockIdx.x*8+wv;
  const int j0=wid*2, j1=j0+1;
  float w[8][16];
#pragma unroll
  for(int q=0;q<4;q++)
#pragma unroll
    for(int jj=0;jj<2;jj++){
      const float* p=Weff+(size_t)(q*HCd+j0+jj)*HCd+lane;
#pragma unroll
      for(int e=0;e<16;e++) w[q*2+jj][e]=p[(size_t)e*64];
    }
  const bool hasf=(j0<Hh);
  float fcc0[16], fcc1[16];
  if(hasf){
    const float* p0=fccw+(size_t)j0*HCd+lane;
    const float* p1=fccw+(size_t)j1*HCd+lane;
#pragma unroll
    for(int e=0;e<16;e++){ fcc0[e]=p0[(size_t)e*64]; fcc1[e]=p1[(size_t)e*64]; }
  } else {
#pragma unroll
    for(int e=0;e<16;e++){ fcc0[e]=0.f; fcc1[e]=0.f; }
  }
  float fb0=hasf?fccb[j0]:0.f, fb1=hasf?fccb[j1]:0.f;
  int cond=condp[0];
  float cd0=hasf?0.f:cemb[cond*Cc+(j0-Hh)];
  float cd1=hasf?0.f:cemb[cond*Cc+(j1-Hh)];
  float cv[8];
#pragma unroll
  for(int r=0;r<8;r++) cv[r]=cvec[(r>>1)*HCd+j0+(r&1)];
  float xg[8];
  { const float* px=Xg+(size_t)1*G4;
#pragma unroll
    for(int r=0;r<8;r++) xg[r]=px[(r>>1)*HCd+j0+(r&1)]; }
  const int i0=tid*2, i1=i0+1;

  for(int s=2;s<=NSD;s++){
    uint4v v;
    unsigned* st=dstate+((s-1)&1)*2*HCd;
    if(s==2){ v=*(const uint4v*)(st+4*tid); }   // S_1 from k_dec0
    else{
      const unsigned expp=(unsigned)(((s-1)>>1)&1);
      for(;;){
        v=ld_uc4(st+4*tid);
        if((((v.x^expp)|(v.y^expp)|(v.z^expp)|(v.w^expp))&1u)==0u) break;
        __builtin_amdgcn_s_sleep(1);
      }
    }
    float* hl=hlds[(s-1)&1]; float* cl=clds[(s-1)&1];
    hl[i0]=__uint_as_float(v.x); cl[i0]=__uint_as_float(v.y);
    hl[i1]=__uint_as_float(v.z); cl[i1]=__uint_as_float(v.w);
    __syncthreads();
    float hseg[16], cseg[16];
#pragma unroll
    for(int e=0;e<16;e++){ hseg[e]=hl[lane+64*e]; cseg[e]=cl[lane+64*e]; }
    float d[8]; float s8=0.f, s9=0.f;
#pragma unroll
    for(int r=0;r<8;r++){ float sacc=0.f;
#pragma unroll
      for(int e=0;e<16;e++) sacc+=w[r][e]*hseg[e];
      d[r]=sacc; }
    if(hasf){
#pragma unroll
      for(int e=0;e<16;e++){ s8+=fcc0[e]*cseg[e]; s9+=fcc1[e]*cseg[e]; }
    }
#pragma unroll
    for(int r=0;r<8;r++) d[r]=wave_reduce(d[r]);
    s8=wave_reduce(s8); s9=wave_reduce(s9);
    float gi0=d[0]+xg[0]+cv[0], gi1=d[1]+xg[1]+cv[1];
    float gf0=d[2]+xg[2]+cv[2], gf1=d[3]+xg[3]+cv[3];
    float gg0=d[4]+xg[4]+cv[4], gg1=d[5]+xg[5]+cv[5];
    float go0=d[6]+xg[6]+cv[6], go1=d[7]+xg[7]+cv[7];
    if(s<NSD){
      const float* px=Xg+(size_t)s*G4;
#pragma unroll
      for(int r=0;r<8;r++) xg[r]=px[(r>>1)*HCd+j0+(r&1)];
    }
    float cc0=hasf?(s8+fb0):cd0;
    float cc1=hasf?(s9+fb1):cd1;
    float cn0=sigmoidf_(gf0)*cc0+sigmoidf_(gi0)*tanhf(gg0);
    float hn0=sigmoidf_(go0)*tanhf(cn0);
    float cn1=sigmoidf_(gf1)*cc1+sigmoidf_(gi1)*tanhf(gg1);
    float hn1=sigmoidf_(go1)*tanhf(cn1);
    unsigned wpar=(unsigned)((s>>1)&1);
    if(lane==0){
      uint4v pk;
      pk.x=(__float_as_uint(hn0)&~1u)|wpar;
      pk.y=(__float_as_uint(cn0)&~1u)|wpar;
      pk.z=(__float_as_uint(hn1)&~1u)|wpar;
      pk.w=(__float_as_uint(cn1)&~1u)|wpar;
      st_uc4(dstate+(s&1)*2*HCd+2*j0,pk);
      Hmat[(size_t)(s-1)*HCd+j0]=hn0; Hmat[(size_t)(s-1)*HCd+j1]=hn1;
    }
  }
}

// ---------------- logits GEMM via bf16 MFMA (C = A·B^T + bias, fp32 acc) ----------------
// A: Mx1024 fp32 (Hmat rows), B: 32000x1024 fp32 (out_w). Converted to bf16 in staging.
#define TBM 128
#define TBN 128
#define TBK 32
__global__ __launch_bounds__(256) void k_gemm_mfma(
    const float* __restrict__ A, const float* __restrict__ B,
    const float* __restrict__ bias, float* __restrict__ Cm, int M)
{
  __shared__ ushort As[TBM*TBK];   // row*32 + k, swizzled 16B units
  __shared__ ushort Bs[TBN*TBK];
  int tid=threadIdx.x;
  int m0=blockIdx.x*TBM, n0=blockIdx.y*TBN;
  int wid=tid>>6, lane=tid&63;
  int wm=wid>>1, wn=wid&1;
  int r15=lane&15, g=lane>>4;
  f32x4 acc[4][4]={};
  int srow=tid>>1, shalf=tid&1;          // 2 threads/row, 16 floats each
  const float* aptr=A+(size_t)(m0+srow)*HCd + shalf*16;
  const float* bptr=B+(size_t)(n0+srow)*HCd + shalf*16;
  bool aok=(m0+srow)<M;
  float bj[4];
#pragma unroll
  for(int j=0;j<4;j++) bj[j]=bias[n0+wn*64+j*16+r15];

  for(int k0=0;k0<HCd;k0+=TBK){
    float4 va0={0,0,0,0},va1={0,0,0,0},va2={0,0,0,0},va3={0,0,0,0};
    if(aok){
      va0=*(const float4*)(aptr+k0);   va1=*(const float4*)(aptr+k0+4);
      va2=*(const float4*)(aptr+k0+8); va3=*(const float4*)(aptr+k0+12);
    }
    float4 vb0=*(const float4*)(bptr+k0),   vb1=*(const float4*)(bptr+k0+4);
    float4 vb2=*(const float4*)(bptr+k0+8), vb3=*(const float4*)(bptr+k0+12);
    uint4v pa0={pk_bf16(va0.x,va0.y),pk_bf16(va0.z,va0.w),pk_bf16(va1.x,va1.y),pk_bf16(va1.z,va1.w)};
    uint4v pa1={pk_bf16(va2.x,va2.y),pk_bf16(va2.z,va2.w),pk_bf16(va3.x,va3.y),pk_bf16(va3.z,va3.w)};
    uint4v pb0={pk_bf16(vb0.x,vb0.y),pk_bf16(vb0.z,vb0.w),pk_bf16(vb1.x,vb1.y),pk_bf16(vb1.z,vb1.w)};
    uint4v pb1={pk_bf16(vb2.x,vb2.y),pk_bf16(vb2.z,vb2.w),pk_bf16(vb3.x,vb3.y),pk_bf16(vb3.z,vb3.w)};
    int sx=(srow>>1)&3;
    int u0=(shalf*2+0)^sx, u1=(shalf*2+1)^sx;   // swizzled 16B-unit index
    *(uint4v*)&As[srow*32+u0*8]=pa0; *(uint4v*)&As[srow*32+u1*8]=pa1;
    *(uint4v*)&Bs[srow*32+u0*8]=pb0; *(uint4v*)&Bs[srow*32+u1*8]=pb1;
    __syncthreads();
    bf16x8 af[4], bf[4];
#pragma unroll
    for(int i=0;i<4;i++){
      int ra=wm*64+i*16+r15;
      af[i]=*(const bf16x8*)&As[ra*32+((g^((ra>>1)&3))<<3)];
      int rb=wn*64+i*16+r15;
      bf[i]=*(const bf16x8*)&Bs[rb*32+((g^((rb>>1)&3))<<3)];
    }
#pragma unroll
    for(int i=0;i<4;i++)
#pragma unroll
      for(int j=0;j<4;j++)
        acc[i][j]=__builtin_amdgcn_mfma_f32_16x16x32_bf16(af[i],bf[j],acc[i][j],0,0,0);
    __syncthreads();
  }
#pragma unroll
  for(int i=0;i<4;i++){
    int grow0=m0+wm*64+i*16+g*4;
#pragma unroll
    for(int j=0;j<4;j++){
      int gcol=n0+wn*64+j*16+r15;
#pragma unroll
      for(int r=0;r<4;r++){
        int grow=grow0+r;
        if(grow<M) Cm[(size_t)grow*VSZ+gcol]=acc[i][j][r]+bj[j];
      }
    }
  }
}

// per-row cross-entropy, single-pass online softmax
__global__ __launch_bounds__(256) void k_ce(const float* __restrict__ logits,
    const int* __restrict__ tok, int base, float* __restrict__ ce)
{
  int r=blockIdx.x;
  const float* row=logits+(size_t)r*VSZ;
  int tid=threadIdx.x, lane=tid&63, wv=tid>>6;
  float m=-1e30f, s=0.f;
  for(int i=tid;i<VSZ;i+=256){
    float v=row[i];
    if(v>m){ s=s*__expf(m-v)+1.f; m=v; }
    else s+=__expf(v-m);
  }
#pragma unroll
  for(int o=32;o;o>>=1){
    float mo=__shfl_xor(m,o,64), so=__shfl_xor(s,o,64);
    float mn=fmaxf(m,mo);
    s=s*__expf(m-mn)+so*__expf(mo-mn);
    m=mn;
  }
  __shared__ float smm[4], sms[4];
  if(lane==0){ smm[wv]=m; sms[wv]=s; }
  __syncthreads();
  if(tid==0){
    float M2=fmaxf(fmaxf(smm[0],smm[1]),fmaxf(smm[2],smm[3]));
    float S2=sms[0]*__expf(smm[0]-M2)+sms[1]*__expf(smm[1]-M2)
            +sms[2]*__expf(smm[2]-M2)+sms[3]*__expf(smm[3]-M2);
    int tgt=tok[base+r+1];
    ce[base+r]=M2+logf(S2)-row[tgt];
  }
}

__global__ __launch_bounds__(256) void k_final(const float* __restrict__ ce,
    const float* __restrict__ klh, const float* __restrict__ klc,
    const float* __restrict__ kldw, float* __restrict__ outp)
{
  int tid=threadIdx.x, lane=tid&63, wv=tid>>6;
  float s0=0,s1=0,s2=0;
  for(int i=tid;i<NSD;i+=256) s0+=ce[i];
  for(int i=tid;i<Hh;i+=256){ s1+=klh[i]; s2+=klc[i]; }
  s0=wave_reduce(s0); s1=wave_reduce(s1); s2=wave_reduce(s2);
  __shared__ float sm[3][4];
  if(lane==0){ sm[0][wv]=s0; sm[1][wv]=s1; sm[2][wv]=s2; }
  __syncthreads();
  if(tid==0){
    float ces=sm[0][0]+sm[0][1]+sm[0][2]+sm[0][3];
    float kh =sm[1][0]+sm[1][1]+sm[1][2]+sm[1][3];
    float kc =sm[2][0]+sm[2][1]+sm[2][2]+sm[2][3];
    float rec=ces/(float)NSD;
    outp[0]=rec+(kh+kc)*kldw[0];
    outp[1]=rec; outp[2]=kh; outp[3]=kc;
  }
}

extern "C" void kernel_launch(void* const* d_in, const int* in_sizes, int n_in,
                              void* d_out, int out_size, void* d_ws, size_t ws_size,
                              hipStream_t stream) {
  const int*   tok   =(const int*)  d_in[0];
  const int*   cond  =(const int*)  d_in[1];
  const float* eps_h =(const float*)d_in[2];
  const float* eps_c =(const float*)d_in[3];
  const float* kldw  =(const float*)d_in[4];
  const float* enc_embed=(const float*)d_in[5];
  const float* enc_cemb =(const float*)d_in[6];
  const float* enc_Wih  =(const float*)d_in[7];
  const float* enc_Whh  =(const float*)d_in[8];
  const float* enc_bih  =(const float*)d_in[9];
  const float* enc_bhh  =(const float*)d_in[10];
  const float* fc_mh_w=(const float*)d_in[11];
  const float* fc_mh_b=(const float*)d_in[12];
  const float* fc_lh_w=(const float*)d_in[13];
  const float* fc_lh_b=(const float*)d_in[14];
  const float* fc_mc_w=(const float*)d_in[15];
  const float* fc_mc_b=(const float*)d_in[16];
  const float* fc_lc_w=(const float*)d_in[17];
  const float* fc_lc_b=(const float*)d_in[18];
  const float* dec_embed=(const float*)d_in[19];
  const float* dec_cemb =(const float*)d_in[20];
  const float* dec_Wih  =(const float*)d_in[21];
  const float* dec_Whh  =(const float*)d_in[22];
  const float* dec_bih  =(const float*)d_in[23];
  const float* dec_bhh  =(const float*)d_in[24];
  const float* fc_h_w=(const float*)d_in[25];
  const float* fc_h_b=(const float*)d_in[26];
  const float* fc_c_w=(const float*)d_in[27];
  const float* fc_c_b=(const float*)d_in[28];
  const float* out_w=(const float*)d_in[29];
  const float* out_b=(const float*)d_in[30];

  float* ws=(float*)d_ws;
  size_t off=0;
  unsigned* estate=(unsigned*)(ws+off); off+=2*HCd;
  unsigned* dstate=(unsigned*)(ws+off); off+=4*HCd;
  float* cvec=ws+off; off+=G4;
  float* Weff=ws+off; off+=(size_t)G4*HCd;
  float* hT  =ws+off; off+=HCd;
  float* cT  =ws+off; off+=HCd;
  float* klh =ws+off; off+=Hh;
  float* klc =ws+off; off+=Hh;
  float* Hmat=ws+off; off+=(size_t)NSD*HCd;
  float* ce  =ws+off; off+=2048;
  float* X   =ws+off;                       // shared region: Xenc / Xdec / lbuf
  size_t avail=ws_size/4;
  size_t region=(avail>off)?(avail-off):0;
  int chunk=256;
  if((size_t)chunk*VSZ>region){
    chunk=(int)(region/(size_t)VSZ);
    if(chunk<1) chunk=1;
  }
  float* lbuf=X;

  k_init3<<<1,256,0,stream>>>(estate,enc_cemb,cond);
  k_dconst<<<64,256,0,stream>>>(dec_Whh,fc_h_b,dec_cemb,cond,cvec);
  { dim3 g(G4/GBM, HCd/GBN);
    k_weff<<<g,256,0,stream>>>(dec_Whh,fc_h_w,Weff); }
  { dim3 g((NSE+GBM-1)/GBM, G4/GBN);        // Xenc
    k_xgemm<<<g,256,0,stream>>>(enc_embed,enc_Wih,enc_bih,enc_bhh,tok,1,NSE,X); }
  k_enc3<<<EB,ET,0,stream>>>(X,enc_Whh,estate,hT,cT);
  k_head<<<Hh,256,0,stream>>>(hT,cT,fc_mh_w,fc_mh_b,fc_lh_w,fc_lh_b,
                              fc_mc_w,fc_mc_b,fc_lc_w,fc_lc_b,
                              eps_h,eps_c,dec_cemb,cond,dstate,klh,klc);
  { dim3 g((NSD+GBM-1)/GBM, G4/GBN);        // Xdec (overwrites Xenc — encoder done)
    k_xgemm<<<g,256,0,stream>>>(dec_embed,dec_Wih,dec_bih,dec_bhh,tok,0,NSD,X); }
  k_dec0<<<256,256,0,stream>>>(X,dec_Whh,dstate,dstate+2*HCd,Hmat);
  k_dec3<<<EB,ET,0,stream>>>(X,Weff,cvec,fc_c_w,fc_c_b,dec_cemb,cond,dstate,Hmat);
  for(int base=0;base<NSD;base+=chunk){     // lbuf overlays X — decoder done
    int rows=NSD-base; if(rows>chunk) rows=chunk;
    dim3 g((rows+TBM-1)/TBM, VSZ/TBN);
    k_gemm_mfma<<<g,256,0,stream>>>(Hmat+(size_t)base*HCd,out_w,out_b,lbuf,rows);
    k_ce<<<rows,256,0,stream>>>(lbuf,tok,base,ce);
  }
  k_final<<<1,256,0,stream>>>(ce,klh,klc,kldw,(float*)d_out);
}

// Round 6
// 13610.298 us; speedup vs baseline: 6.8167x; 1.3008x over previous
//
#include <hip/hip_runtime.h>
#include <math.h>

// Problem sizes (fixed)
#define VSZ 32000
#define Hh  768
#define Cc  256
#define HCd 1024
#define G4  4096
#define NSE 2046   // encoder steps
#define NSD 2047   // decoder steps

// Persistent scan shape: 64 blocks x 512 threads (8 waves) = 512 waves,
// each wave owns 2 output elements (8 gate rows). Liveness needs only
// co-residency (64 blocks <= 256 CUs) — no placement assumptions.
#define EB 64
#define ET 512

typedef __attribute__((ext_vector_type(4))) unsigned uint4v;
typedef __attribute__((ext_vector_type(2))) unsigned uint2v;
typedef __attribute__((ext_vector_type(8))) short bf16x8;
typedef __attribute__((ext_vector_type(4))) float f32x4;

__device__ __forceinline__ float sigmoidf_(float x){ return 1.0f/(1.0f+expf(-x)); }

__device__ __forceinline__ float wave_reduce(float v){
#pragma unroll
  for(int o=32;o;o>>=1) v += __shfl_xor(v,o,64);
  return v;
}

// Reduce 64 lanes; total valid in lane 0 (lanes 0..31 hold the full sum).
// xor1/xor2 via DPP quad_perm (VALU pipe), xor4/8/16 via ds_swizzle, +upper via readlane.
__device__ __forceinline__ float redl0(float v){
  int x;
  x=__builtin_amdgcn_update_dpp(0,__float_as_int(v),0xB1,0xf,0xf,true); v+=__int_as_float(x); // ^1
  x=__builtin_amdgcn_update_dpp(0,__float_as_int(v),0x4E,0xf,0xf,true); v+=__int_as_float(x); // ^2
  v+=__int_as_float(__builtin_amdgcn_ds_swizzle(__float_as_int(v),0x101F)); // ^4
  v+=__int_as_float(__builtin_amdgcn_ds_swizzle(__float_as_int(v),0x201F)); // ^8
  v+=__int_as_float(__builtin_amdgcn_ds_swizzle(__float_as_int(v),0x401F)); // ^16
  v+=__int_as_float(__builtin_amdgcn_readlane(__float_as_int(v),32));       // + upper half
  return v;
}

// Uncached (coherence-point) vector load/store: single transaction for the
// whole per-thread state slice. Per-dword LSB parity makes each dword
// self-validating, so no multi-word atomicity is required.
__device__ __forceinline__ uint4v ld_uc4(const unsigned* p){
  uint4v r;
  asm volatile("global_load_dwordx4 %0, %1, off sc0 sc1\n\ts_waitcnt vmcnt(0)"
               : "=v"(r) : "v"(p) : "memory");
  return r;
}
__device__ __forceinline__ uint2v ld_uc2(const unsigned* p){
  uint2v r;
  asm volatile("global_load_dwordx2 %0, %1, off sc0 sc1\n\ts_waitcnt vmcnt(0)"
               : "=v"(r) : "v"(p) : "memory");
  return r;
}
__device__ __forceinline__ void st_uc4(unsigned* p, uint4v v){
  asm volatile("global_store_dwordx4 %0, %1, off sc0 sc1" :: "v"(p), "v"(v) : "memory");
}
__device__ __forceinline__ void st_uc2(unsigned* p, uint2v v){
  asm volatile("global_store_dwordx2 %0, %1, off sc0 sc1" :: "v"(p), "v"(v) : "memory");
}

// round-to-nearest-even fp32->bf16, pack two into a dword
__device__ __forceinline__ unsigned pk_bf16(float a, float b){
  unsigned ua=__float_as_uint(a); ua += 0x7fffu + ((ua>>16)&1u);
  unsigned ub=__float_as_uint(b); ub += 0x7fffu + ((ub>>16)&1u);
  return (ua>>16) | (ub & 0xffff0000u);
}

// init: encoder S_0 into estate slot0 (parity 0), slot1 poisoned to parity 1
__global__ void k_init3(unsigned* estate, const float* __restrict__ cemb,
                        const int* __restrict__ condp){
  int tid=threadIdx.x;
  int cond=condp[0];
  for(int i=tid;i<HCd;i+=256){
    float v=(i<Hh)?0.f:cemb[cond*Cc+(i-Hh)];
    estate[i]=__float_as_uint(v)&~1u;   // S_0, parity 0
    estate[HCd+i]=1u;                   // stale slot: parity 1
  }
}

// dec_const[r] = dec_W_hh[r,0:768]·fc_h_b + dec_W_hh[r,768:1024]·cd
__global__ __launch_bounds__(256) void k_dconst(const float* __restrict__ Whh,
    const float* __restrict__ fhb, const float* __restrict__ cemb,
    const int* __restrict__ condp, float* __restrict__ cvec){
  int lane=threadIdx.x&63, wv=threadIdx.x>>6;
  int wgid=blockIdx.x*4+wv;
  int cond=condp[0];
  for(int r=wgid;r<G4;r+=256){
    const float* row=Whh+(size_t)r*HCd;
    float s=0.f;
    for(int k=lane;k<Hh;k+=64) s+=row[k]*fhb[k];
    for(int k=lane;k<Cc;k+=64) s+=row[Hh+k]*cemb[cond*Cc+k];
    s=wave_reduce(s);
    if(lane==0) cvec[r]=s;
  }
}

#define GBM 128
#define GBN 128
#define GBK 16

// Weff[r,k] = sum_{i<768} dec_W_hh[r,i]*fc_h_w[i,k]   (M=4096,N=1024,K=768)
__global__ __launch_bounds__(256) void k_weff(const float* __restrict__ A,
    const float* __restrict__ B, float* __restrict__ Cm){
  __shared__ float As[GBK][GBM];
  __shared__ float Bs[GBK][GBN];
  int tid=threadIdx.x;
  int m0=blockIdx.x*GBM, n0=blockIdx.y*GBN;
  int tm=tid>>4, tn=tid&15;
  float acc[8][8]={};
  for(int k0=0;k0<Hh;k0+=GBK){
#pragma unroll
    for(int u=0;u<2;u++){
      int idx=tid*2+u;
      int row=idx>>2, q=idx&3;
      float4 v=*(const float4*)(A+(size_t)(m0+row)*HCd + k0+q*4);
      As[q*4+0][row]=v.x; As[q*4+1][row]=v.y; As[q*4+2][row]=v.z; As[q*4+3][row]=v.w;
      int kk=idx>>5, nc=idx&31;
      float4 w=*(const float4*)(B+(size_t)(k0+kk)*HCd + n0+nc*4);
      *(float4*)&Bs[kk][nc*4]=w;
    }
    __syncthreads();
#pragma unroll
    for(int kk=0;kk<GBK;kk++){
      float a[8],b[8];
      *(float4*)&a[0]=*(float4*)&As[kk][tm*8]; *(float4*)&a[4]=*(float4*)&As[kk][tm*8+4];
      *(float4*)&b[0]=*(float4*)&Bs[kk][tn*8]; *(float4*)&b[4]=*(float4*)&Bs[kk][tn*8+4];
#pragma unroll
      for(int i=0;i<8;i++)
#pragma unroll
        for(int j=0;j<8;j++) acc[i][j]+=a[i]*b[j];
    }
    __syncthreads();
  }
#pragma unroll
  for(int i=0;i<8;i++)
#pragma unroll
    for(int j=0;j<8;j++)
      Cm[(size_t)(m0+tm*8+i)*HCd + n0+tn*8+j]=acc[i][j];
}

// Encoder X (fp32 tile GEMM — kept fp32: kl_h/kl_c precision headroom is thin)
__global__ __launch_bounds__(256) void k_xgemm(
    const float* __restrict__ emb, const float* __restrict__ Wih,
    const float* __restrict__ b1, const float* __restrict__ b2,
    const int* __restrict__ tok, int tshift, int M,
    float* __restrict__ X)
{
  __shared__ float As[GBK][GBM];
  __shared__ float Bs[GBK][GBN];
  int tid=threadIdx.x;
  int m0=blockIdx.x*GBM, n0=blockIdx.y*GBN;
  int tm=tid>>4, tn=tid&15;
  int arow=m0+(tid>>1);
  int atok=(arow<M)?tok[arow+tshift]:0;
  const float* abase=emb+(size_t)atok*HCd+(tid&1)*8;
  const float* bbase=Wih+(size_t)(n0+(tid>>1))*HCd+(tid&1)*8;
  int srow=tid>>1;
  float acc[8][8]={};
  for(int k0=0;k0<HCd;k0+=GBK){
#pragma unroll
    for(int u=0;u<2;u++){
      int q=2*(tid&1)+u;
      float4 v={0,0,0,0};
      if(arow<M) v=*(const float4*)(abase+k0+u*4);
      As[q*4+0][srow]=v.x; As[q*4+1][srow]=v.y; As[q*4+2][srow]=v.z; As[q*4+3][srow]=v.w;
      float4 w=*(const float4*)(bbase+k0+u*4);
      Bs[q*4+0][srow]=w.x; Bs[q*4+1][srow]=w.y; Bs[q*4+2][srow]=w.z; Bs[q*4+3][srow]=w.w;
    }
    __syncthreads();
#pragma unroll
    for(int kk=0;kk<GBK;kk++){
      float a[8],b[8];
      *(float4*)&a[0]=*(float4*)&As[kk][tm*8]; *(float4*)&a[4]=*(float4*)&As[kk][tm*8+4];
      *(float4*)&b[0]=*(float4*)&Bs[kk][tn*8]; *(float4*)&b[4]=*(float4*)&Bs[kk][tn*8+4];
#pragma unroll
      for(int i=0;i<8;i++)
#pragma unroll
        for(int j=0;j<8;j++) acc[i][j]+=a[i]*b[j];
    }
    __syncthreads();
  }
#pragma unroll
  for(int i=0;i<8;i++){
    int m=m0+tm*8+i; if(m>=M) continue;
#pragma unroll
    for(int j=0;j<8;j++){
      int n=n0+tn*8+j;
      X[(size_t)m*G4+n]=acc[i][j]+b1[n]+b2[n];
    }
  }
}

#define TBM 128
#define TBN 128
#define TBK 32

// Decoder X via bf16 MFMA: X[m][n] = emb[tok[m]]·Wih_row(n) + b1[n]+b2[n]
__global__ __launch_bounds__(256) void k_xgemm_mfma(
    const float* __restrict__ emb, const float* __restrict__ Wih,
    const float* __restrict__ b1, const float* __restrict__ b2,
    const int* __restrict__ tok, int M, float* __restrict__ X)
{
  __shared__ ushort As[TBM*TBK];
  __shared__ ushort Bs[TBN*TBK];
  int tid=threadIdx.x;
  int m0=blockIdx.x*TBM, n0=blockIdx.y*TBN;
  int wid=tid>>6, lane=tid&63;
  int wm=wid>>1, wn=wid&1;
  int r15=lane&15, g=lane>>4;
  f32x4 acc[4][4]={};
  int srow=tid>>1, shalf=tid&1;
  int arow=m0+srow;
  int atok=(arow<M)?tok[arow]:0;
  const float* aptr=emb+(size_t)atok*HCd + shalf*16;
  const float* bptr=Wih+(size_t)(n0+srow)*HCd + shalf*16;
  bool aok=arow<M;
  float bj[4];
#pragma unroll
  for(int j=0;j<4;j++){ int n=n0+wn*64+j*16+r15; bj[j]=b1[n]+b2[n]; }

  for(int k0=0;k0<HCd;k0+=TBK){
    float4 va0={0,0,0,0},va1={0,0,0,0},va2={0,0,0,0},va3={0,0,0,0};
    if(aok){
      va0=*(const float4*)(aptr+k0);   va1=*(const float4*)(aptr+k0+4);
      va2=*(const float4*)(aptr+k0+8); va3=*(const float4*)(aptr+k0+12);
    }
    float4 vb0=*(const float4*)(bptr+k0),   vb1=*(const float4*)(bptr+k0+4);
    float4 vb2=*(const float4*)(bptr+k0+8), vb3=*(const float4*)(bptr+k0+12);
    uint4v pa0={pk_bf16(va0.x,va0.y),pk_bf16(va0.z,va0.w),pk_bf16(va1.x,va1.y),pk_bf16(va1.z,va1.w)};
    uint4v pa1={pk_bf16(va2.x,va2.y),pk_bf16(va2.z,va2.w),pk_bf16(va3.x,va3.y),pk_bf16(va3.z,va3.w)};
    uint4v pb0={pk_bf16(vb0.x,vb0.y),pk_bf16(vb0.z,vb0.w),pk_bf16(vb1.x,vb1.y),pk_bf16(vb1.z,vb1.w)};
    uint4v pb1={pk_bf16(vb2.x,vb2.y),pk_bf16(vb2.z,vb2.w),pk_bf16(vb3.x,vb3.y),pk_bf16(vb3.z,vb3.w)};
    int sx=(srow>>1)&3;
    int u0=(shalf*2+0)^sx, u1=(shalf*2+1)^sx;
    *(uint4v*)&As[srow*32+u0*8]=pa0; *(uint4v*)&As[srow*32+u1*8]=pa1;
    *(uint4v*)&Bs[srow*32+u0*8]=pb0; *(uint4v*)&Bs[srow*32+u1*8]=pb1;
    __syncthreads();
    bf16x8 af[4], bf[4];
#pragma unroll
    for(int i=0;i<4;i++){
      int ra=wm*64+i*16+r15;
      af[i]=*(const bf16x8*)&As[ra*32+((g^((ra>>1)&3))<<3)];
      int rb=wn*64+i*16+r15;
      bf[i]=*(const bf16x8*)&Bs[rb*32+((g^((rb>>1)&3))<<3)];
    }
#pragma unroll
    for(int i=0;i<4;i++)
#pragma unroll
      for(int j=0;j<4;j++)
        acc[i][j]=__builtin_amdgcn_mfma_f32_16x16x32_bf16(af[i],bf[j],acc[i][j],0,0,0);
    __syncthreads();
  }
#pragma unroll
  for(int i=0;i<4;i++){
    int grow0=m0+wm*64+i*16+g*4;
#pragma unroll
    for(int j=0;j<4;j++){
      int gcol=n0+wn*64+j*16+r15;
#pragma unroll
      for(int r=0;r<4;r++){
        int grow=grow0+r;
        if(grow<M) X[(size_t)grow*G4+gcol]=acc[i][j][r]+bj[j];
      }
    }
  }
}

// ---------------- Encoder persistent scan (seqlock-LSB, 1 uncached ld/step) ----------------
__global__ __launch_bounds__(ET,2) void k_enc3(
    const float* __restrict__ Xg,     // [NSE][4096], bias folded in
    const float* __restrict__ Whh,    // [4096][1024]
    unsigned* estate,                 // [2][1024] h (fp32 bits, LSB=parity)
    float* hT, float* cT)
{
  __shared__ float hlds[2][HCd];
  const int tid=threadIdx.x, lane=tid&63, wv=tid>>6;
  const int wid=blockIdx.x*8+wv;
  const int j0=wid*2, j1=j0+1;
  float w[8][16];
#pragma unroll
  for(int q=0;q<4;q++)
#pragma unroll
    for(int jj=0;jj<2;jj++){
      const float* p=Whh+(size_t)(q*HCd+j0+jj)*HCd+lane;
#pragma unroll
      for(int e=0;e<16;e++) w[q*2+jj][e]=p[(size_t)e*64];
    }
  float xg[8];
#pragma unroll
  for(int r=0;r<8;r++) xg[r]=Xg[(r>>1)*HCd+j0+(r&1)];
  float c0=0.f,c1=0.f;
  const int i0=tid*2, i1=i0+1;

  for(int s=1;s<=NSE;s++){
    uint2v v;
    unsigned* src=estate+((s-1)&1)*HCd;
    if(s==1){ v.x=src[i0]; v.y=src[i1]; }       // S_0 from prior kernel
    else{
      const unsigned expp=(unsigned)(((s-1)>>1)&1);
      for(;;){
        v=ld_uc2(src+i0);
        if((((v.x^expp)|(v.y^expp))&1u)==0u) break;
        __builtin_amdgcn_s_sleep(1);
      }
    }
    float* hl=hlds[(s-1)&1];
    hl[i0]=__uint_as_float(v.x); hl[i1]=__uint_as_float(v.y);
    __syncthreads();
    if(s==1){ c0=hl[j0]; c1=hl[j1]; }           // h0 == c0
    float hseg[16];
#pragma unroll
    for(int e=0;e<16;e++) hseg[e]=hl[lane+64*e];
    float d[8];
#pragma unroll
    for(int r=0;r<8;r++){ float sacc=0.f;
#pragma unroll
      for(int e=0;e<16;e++) sacc+=w[r][e]*hseg[e];
      d[r]=sacc; }
#pragma unroll
    for(int r=0;r<8;r++) d[r]=redl0(d[r]);      // valid in lane 0
    float gi0=d[0]+xg[0], gi1=d[1]+xg[1];
    float gf0=d[2]+xg[2], gf1=d[3]+xg[3];
    float gg0=d[4]+xg[4], gg1=d[5]+xg[5];
    float go0=d[6]+xg[6], go1=d[7]+xg[7];
    if(s<NSE){
      const float* px=Xg+(size_t)s*G4;
#pragma unroll
      for(int r=0;r<8;r++) xg[r]=px[(r>>1)*HCd+j0+(r&1)];
    }
    c0=sigmoidf_(gf0)*c0+sigmoidf_(gi0)*tanhf(gg0);
    float h0=sigmoidf_(go0)*tanhf(c0);
    c1=sigmoidf_(gf1)*c1+sigmoidf_(gi1)*tanhf(gg1);
    float h1=sigmoidf_(go1)*tanhf(c1);
    unsigned wpar=(unsigned)((s>>1)&1);
    if(lane==0){
      uint2v pk;
      pk.x=(__float_as_uint(h0)&~1u)|wpar;
      pk.y=(__float_as_uint(h1)&~1u)|wpar;
      st_uc2(estate+(s&1)*HCd+j0,pk);
      if(s==NSE){ hT[j0]=h0; hT[j1]=h1; cT[j0]=c0; cT[j1]=c1; }
    }
  }
}

// ---------------- VAE heads ----------------
__global__ __launch_bounds__(256) void k_head(
    const float* __restrict__ hT, const float* __restrict__ cT,
    const float* __restrict__ mhw, const float* __restrict__ mhb,
    const float* __restrict__ lhw, const float* __restrict__ lhb,
    const float* __restrict__ mcw, const float* __restrict__ mcb,
    const float* __restrict__ lcw, const float* __restrict__ lcb,
    const float* __restrict__ eps_h, const float* __restrict__ eps_c,
    const float* __restrict__ cemb, const int* __restrict__ condp,
    unsigned* dstate0, float* klh, float* klc)
{
  int i=blockIdx.x;
  int tid=threadIdx.x, lane=tid&63, wv=tid>>6;
  __shared__ float sm[4];
  const float* Wm=(wv==0)?mhw:(wv==1)?lhw:(wv==2)?mcw:lcw;
  const float* vec=(wv<2)?hT:cT;
  const float* row=Wm+(size_t)i*HCd;
  float s=0.f;
  for(int k=lane;k<HCd;k+=64) s+=row[k]*vec[k];
  s=wave_reduce(s);
  if(lane==0) sm[wv]=s;
  __syncthreads();
  if(tid==0){
    float mh=sm[0]+mhb[i], lh=sm[1]+lhb[i];
    float mc=sm[2]+mcb[i], lc=sm[3]+lcb[i];
    float zhv=eps_h[i]*expf(lh*0.5f)+mh;
    float zcv=eps_c[i]*expf(lc*0.5f)+mc;
    dstate0[2*i]  =__float_as_uint(zhv)&~1u;
    dstate0[2*i+1]=__float_as_uint(zcv)&~1u;
    klh[i]=0.5f*(mh*mh+expf(lh)-1.f-lh);
    klc[i]=0.5f*(mc*mc+expf(lc)-1.f-lc);
    if(i<Cc){
      unsigned cu=__float_as_uint(cemb[condp[0]*Cc+i])&~1u;
      dstate0[2*(Hh+i)]=cu; dstate0[2*(Hh+i)+1]=cu;
    }
  }
}

// decoder step 1: gates = Xdec[0] + WhhO·S0.h; cc = S0.c[j]; writes S_1 (parity 0)
__global__ __launch_bounds__(256) void k_dec0(
    const float* __restrict__ Xg, const float* __restrict__ WhhO,
    const unsigned* __restrict__ dstate0, unsigned* dstate1, float* Hmat)
{
  int tid=threadIdx.x, lane=tid&63, wv=tid>>6;
  int j=blockIdx.x*4+wv;
  float hseg[16];
#pragma unroll
  for(int e=0;e<16;e++) hseg[e]=__uint_as_float(dstate0[2*(lane+64*e)]);
  float g[4];
#pragma unroll
  for(int q=0;q<4;q++){
    const float* p=WhhO+(size_t)(q*HCd+j)*HCd+lane;
    float s=0.f;
#pragma unroll
    for(int e=0;e<16;e++) s+=p[(size_t)e*64]*hseg[e];
    s=wave_reduce(s);
    g[q]=s+Xg[q*HCd+j];
  }
  float cc=__uint_as_float(dstate0[2*j+1]);
  float cn=sigmoidf_(g[1])*cc+sigmoidf_(g[0])*tanhf(g[2]);
  float hn=sigmoidf_(g[3])*tanhf(cn);
  if(lane==0){
    dstate1[2*j]  =__float_as_uint(hn)&~1u;
    dstate1[2*j+1]=__float_as_uint(cn)&~1u;
    Hmat[j]=hn;
  }
}

// ---------------- Decoder persistent scan (s = 2..NSD, 1 uncached ldx4/step) ----------------
__global__ __launch_bounds__(ET,2) void k_dec3(
    const float* __restrict__ Xg,     // [NSD][4096], bias folded
    const float* __restrict__ Weff,
    const float* __restrict__ cvec,
    const float* __restrict__ fccw, const float* __restrict__ fccb,
    const float* __restrict__ cemb, const int* __restrict__ condp,
    unsigned* dstate, float* __restrict__ Hmat)
{
  __shared__ float hlds[2][HCd];
  __shared__ float clds[2][HCd];
  const int tid=threadIdx.x, lane=tid&63, wv=tid>>6;
  const int wid=blockIdx.x*8+wv;
  const int j0=wid*2, j1=j0+1;
  float w[8][16];
#pragma unroll
  for(int q=0;q<4;q++)
#pragma unroll
    for(int jj=0;jj<2;jj++){
      const float* p=Weff+(size_t)(q*HCd+j0+jj)*HCd+lane;
#pragma unroll
      for(int e=0;e<16;e++) w[q*2+jj][e]=p[(size_t)e*64];
    }
  const bool hasf=(j0<Hh);
  float fcc0[16], fcc1[16];
  if(hasf){
    const float* p0=fccw+(size_t)j0*HCd+lane;
    const float* p1=fccw+(size_t)j1*HCd+lane;
#pragma unroll
    for(int e=0;e<16;e++){ fcc0[e]=p0[(size_t)e*64]; fcc1[e]=p1[(size_t)e*64]; }
  } else {
#pragma unroll
    for(int e=0;e<16;e++){ fcc0[e]=0.f; fcc1[e]=0.f; }
  }
  float fb0=hasf?fccb[j0]:0.f, fb1=hasf?fccb[j1]:0.f;
  int cond=condp[0];
  float cd0=hasf?0.f:cemb[cond*Cc+(j0-Hh)];
  float cd1=hasf?0.f:cemb[cond*Cc+(j1-Hh)];
  float cv[8];
#pragma unroll
  for(int r=0;r<8;r++) cv[r]=cvec[(r>>1)*HCd+j0+(r&1)];
  float xg[8];
  { const float* px=Xg+(size_t)1*G4;
#pragma unroll
    for(int r=0;r<8;r++) xg[r]=px[(r>>1)*HCd+j0+(r&1)]; }
  const int i0=tid*2, i1=i0+1;

  for(int s=2;s<=NSD;s++){
    uint4v v;
    unsigned* st=dstate+((s-1)&1)*2*HCd;
    if(s==2){ v=*(const uint4v*)(st+4*tid); }   // S_1 from k_dec0
    else{
      const unsigned expp=(unsigned)(((s-1)>>1)&1);
      for(;;){
        v=ld_uc4(st+4*tid);
        if((((v.x^expp)|(v.y^expp)|(v.z^expp)|(v.w^expp))&1u)==0u) break;
        __builtin_amdgcn_s_sleep(1);
      }
    }
    float* hl=hlds[(s-1)&1]; float* cl=clds[(s-1)&1];
    hl[i0]=__uint_as_float(v.x); cl[i0]=__uint_as_float(v.y);
    hl[i1]=__uint_as_float(v.z); cl[i1]=__uint_as_float(v.w);
    __syncthreads();
    float hseg[16], cseg[16];
#pragma unroll
    for(int e=0;e<16;e++){ hseg[e]=hl[lane+64*e]; cseg[e]=cl[lane+64*e]; }
    float d[8]; float s8=0.f, s9=0.f;
#pragma unroll
    for(int r=0;r<8;r++){ float sacc=0.f;
#pragma unroll
      for(int e=0;e<16;e++) sacc+=w[r][e]*hseg[e];
      d[r]=sacc; }
#pragma unroll
    for(int r=0;r<8;r++) d[r]=redl0(d[r]);      // valid in lane 0
    if(hasf){
#pragma unroll
      for(int e=0;e<16;e++){ s8+=fcc0[e]*cseg[e]; s9+=fcc1[e]*cseg[e]; }
      s8=redl0(s8); s9=redl0(s9);
    }
    float gi0=d[0]+xg[0]+cv[0], gi1=d[1]+xg[1]+cv[1];
    float gf0=d[2]+xg[2]+cv[2], gf1=d[3]+xg[3]+cv[3];
    float gg0=d[4]+xg[4]+cv[4], gg1=d[5]+xg[5]+cv[5];
    float go0=d[6]+xg[6]+cv[6], go1=d[7]+xg[7]+cv[7];
    if(s<NSD){
      const float* px=Xg+(size_t)s*G4;
#pragma unroll
      for(int r=0;r<8;r++) xg[r]=px[(r>>1)*HCd+j0+(r&1)];
    }
    float cc0=hasf?(s8+fb0):cd0;
    float cc1=hasf?(s9+fb1):cd1;
    float cn0=sigmoidf_(gf0)*cc0+sigmoidf_(gi0)*tanhf(gg0);
    float hn0=sigmoidf_(go0)*tanhf(cn0);
    float cn1=sigmoidf_(gf1)*cc1+sigmoidf_(gi1)*tanhf(gg1);
    float hn1=sigmoidf_(go1)*tanhf(cn1);
    unsigned wpar=(unsigned)((s>>1)&1);
    if(lane==0){
      uint4v pk;
      pk.x=(__float_as_uint(hn0)&~1u)|wpar;
      pk.y=(__float_as_uint(cn0)&~1u)|wpar;
      pk.z=(__float_as_uint(hn1)&~1u)|wpar;
      pk.w=(__float_as_uint(cn1)&~1u)|wpar;
      st_uc4(dstate+(s&1)*2*HCd+2*j0,pk);
      Hmat[(size_t)(s-1)*HCd+j0]=hn0; Hmat[(size_t)(s-1)*HCd+j1]=hn1;
    }
  }
}

// out_w fp32 -> bf16 (RNE), packed 2/dword
__global__ __launch_bounds__(256) void k_cvtB(const float* __restrict__ B,
    unsigned* __restrict__ Bb){
  size_t idx=(size_t)blockIdx.x*256+threadIdx.x;
  size_t total=(size_t)VSZ*HCd/4;     // float4 units
  for(size_t i=idx;i<total;i+=(size_t)gridDim.x*256){
    float4 v=*(const float4*)(B+i*4);
    Bb[i*2]  =pk_bf16(v.x,v.y);
    Bb[i*2+1]=pk_bf16(v.z,v.w);
  }
}

// ---------------- logits GEMM, B pre-converted bf16 ----------------
__global__ __launch_bounds__(256) void k_gemm2(
    const float* __restrict__ A, const ushort* __restrict__ Bb,
    const float* __restrict__ bias, float* __restrict__ Cm, int M)
{
  __shared__ ushort As[TBM*TBK];
  __shared__ ushort Bs[TBN*TBK];
  int tid=threadIdx.x;
  int m0=blockIdx.x*TBM, n0=blockIdx.y*TBN;
  int wid=tid>>6, lane=tid&63;
  int wm=wid>>1, wn=wid&1;
  int r15=lane&15, g=lane>>4;
  f32x4 acc[4][4]={};
  int srow=tid>>1, shalf=tid&1;
  const float*  aptr=A +(size_t)(m0+srow)*HCd + shalf*16;
  const ushort* bptr=Bb+(size_t)(n0+srow)*HCd + shalf*16;
  bool aok=(m0+srow)<M;
  float bj[4];
#pragma unroll
  for(int j=0;j<4;j++) bj[j]=bias[n0+wn*64+j*16+r15];

  for(int k0=0;k0<HCd;k0+=TBK){
    float4 va0={0,0,0,0},va1={0,0,0,0},va2={0,0,0,0},va3={0,0,0,0};
    if(aok){
      va0=*(const float4*)(aptr+k0);   va1=*(const float4*)(aptr+k0+4);
      va2=*(const float4*)(aptr+k0+8); va3=*(const float4*)(aptr+k0+12);
    }
    uint4v qb0=*(const uint4v*)(bptr+k0);
    uint4v qb1=*(const uint4v*)(bptr+k0+8);
    uint4v pa0={pk_bf16(va0.x,va0.y),pk_bf16(va0.z,va0.w),pk_bf16(va1.x,va1.y),pk_bf16(va1.z,va1.w)};
    uint4v pa1={pk_bf16(va2.x,va2.y),pk_bf16(va2.z,va2.w),pk_bf16(va3.x,va3.y),pk_bf16(va3.z,va3.w)};
    int sx=(srow>>1)&3;
    int u0=(shalf*2+0)^sx, u1=(shalf*2+1)^sx;
    *(uint4v*)&As[srow*32+u0*8]=pa0; *(uint4v*)&As[srow*32+u1*8]=pa1;
    *(uint4v*)&Bs[srow*32+u0*8]=qb0; *(uint4v*)&Bs[srow*32+u1*8]=qb1;
    __syncthreads();
    bf16x8 af[4], bf[4];
#pragma unroll
    for(int i=0;i<4;i++){
      int ra=wm*64+i*16+r15;
      af[i]=*(const bf16x8*)&As[ra*32+((g^((ra>>1)&3))<<3)];
      int rb=wn*64+i*16+r15;
      bf[i]=*(const bf16x8*)&Bs[rb*32+((g^((rb>>1)&3))<<3)];
    }
#pragma unroll
    for(int i=0;i<4;i++)
#pragma unroll
      for(int j=0;j<4;j++)
        acc[i][j]=__builtin_amdgcn_mfma_f32_16x16x32_bf16(af[i],bf[j],acc[i][j],0,0,0);
    __syncthreads();
  }
#pragma unroll
  for(int i=0;i<4;i++){
    int grow0=m0+wm*64+i*16+g*4;
#pragma unroll
    for(int j=0;j<4;j++){
      int gcol=n0+wn*64+j*16+r15;
#pragma unroll
      for(int r=0;r<4;r++){
        int grow=grow0+r;
        if(grow<M) Cm[(size_t)grow*VSZ+gcol]=acc[i][j][r]+bj[j];
      }
    }
  }
}

// ---------------- logits GEMM fallback (in-kernel B conversion) ----------------
__global__ __launch_bounds__(256) void k_gemm_mfma(
    const float* __restrict__ A, const float* __restrict__ B,
    const float* __restrict__ bias, float* __restrict__ Cm, int M)
{
  __shared__ ushort As[TBM*TBK];
  __shared__ ushort Bs[TBN*TBK];
  int tid=threadIdx.x;
  int m0=blockIdx.x*TBM, n0=blockIdx.y*TBN;
  int wid=tid>>6, lane=tid&63;
  int wm=wid>>1, wn=wid&1;
  int r15=lane&15, g=lane>>4;
  f32x4 acc[4][4]={};
  int srow=tid>>1, shalf=tid&1;
  const float* aptr=A+(size_t)(m0+srow)*HCd + shalf*16;
  const float* bptr=B+(size_t)(n0+srow)*HCd + shalf*16;
  bool aok=(m0+srow)<M;
  float bj[4];
#pragma unroll
  for(int j=0;j<4;j++) bj[j]=bias[n0+wn*64+j*16+r15];

  for(int k0=0;k0<HCd;k0+=TBK){
    float4 va0={0,0,0,0},va1={0,0,0,0},va2={0,0,0,0},va3={0,0,0,0};
    if(aok){
      va0=*(const float4*)(aptr+k0);   va1=*(const float4*)(aptr+k0+4);
      va2=*(const float4*)(aptr+k0+8); va3=*(const float4*)(aptr+k0+12);
    }
    float4 vb0=*(const float4*)(bptr+k0),   vb1=*(const float4*)(bptr+k0+4);
    float4 vb2=*(const float4*)(bptr+k0+8), vb3=*(const float4*)(bptr+k0+12);
    uint4v pa0={pk_bf16(va0.x,va0.y),pk_bf16(va0.z,va0.w),pk_bf16(va1.x,va1.y),pk_bf16(va1.z,va1.w)};
    uint4v pa1={pk_bf16(va2.x,va2.y),pk_bf16(va2.z,va2.w),pk_bf16(va3.x,va3.y),pk_bf16(va3.z,va3.w)};
    uint4v pb0={pk_bf16(vb0.x,vb0.y),pk_bf16(vb0.z,vb0.w),pk_bf16(vb1.x,vb1.y),pk_bf16(vb1.z,vb1.w)};
    uint4v pb1={pk_bf16(vb2.x,vb2.y),pk_bf16(vb2.z,vb2.w),pk_bf16(vb3.x,vb3.y),pk_bf16(vb3.z,vb3.w)};
    int sx=(srow>>1)&3;
    int u0=(shalf*2+0)^sx, u1=(shalf*2+1)^sx;
    *(uint4v*)&As[srow*32+u0*8]=pa0; *(uint4v*)&As[srow*32+u1*8]=pa1;
    *(uint4v*)&Bs[srow*32+u0*8]=pb0; *(uint4v*)&Bs[srow*32+u1*8]=pb1;
    __syncthreads();
    bf16x8 af[4], bf[4];
#pragma unroll
    for(int i=0;i<4;i++){
      int ra=wm*64+i*16+r15;
      af[i]=*(const bf16x8*)&As[ra*32+((g^((ra>>1)&3))<<3)];
      int rb=wn*64+i*16+r15;
      bf[i]=*(const bf16x8*)&Bs[rb*32+((g^((rb>>1)&3))<<3)];
    }
#pragma unroll
    for(int i=0;i<4;i++)
#pragma unroll
      for(int j=0;j<4;j++)
        acc[i][j]=__builtin_amdgcn_mfma_f32_16x16x32_bf16(af[i],bf[j],acc[i][j],0,0,0);
    __syncthreads();
  }
#pragma unroll
  for(int i=0;i<4;i++){
    int grow0=m0+wm*64+i*16+g*4;
#pragma unroll
    for(int j=0;j<4;j++){
      int gcol=n0+wn*64+j*16+r15;
#pragma unroll
      for(int r=0;r<4;r++){
        int grow=grow0+r;
        if(grow<M) Cm[(size_t)grow*VSZ+gcol]=acc[i][j][r]+bj[j];
      }
    }
  }
}

// per-row cross-entropy, single-pass online softmax
__global__ __launch_bounds__(256) void k_ce(const float* __restrict__ logits,
    const int* __restrict__ tok, int base, float* __restrict__ ce)
{
  int r=blockIdx.x;
  const float* row=logits+(size_t)r*VSZ;
  int tid=threadIdx.x, lane=tid&63, wv=tid>>6;
  float m=-1e30f, s=0.f;
  for(int i=tid;i<VSZ;i+=256){
    float v=row[i];
    if(v>m){ s=s*__expf(m-v)+1.f; m=v; }
    else s+=__expf(v-m);
  }
#pragma unroll
  for(int o=32;o;o>>=1){
    float mo=__shfl_xor(m,o,64), so=__shfl_xor(s,o,64);
    float mn=fmaxf(m,mo);
    s=s*__expf(m-mn)+so*__expf(mo-mn);
    m=mn;
  }
  __shared__ float smm[4], sms[4];
  if(lane==0){ smm[wv]=m; sms[wv]=s; }
  __syncthreads();
  if(tid==0){
    float M2=fmaxf(fmaxf(smm[0],smm[1]),fmaxf(smm[2],smm[3]));
    float S2=sms[0]*__expf(smm[0]-M2)+sms[1]*__expf(smm[1]-M2)
            +sms[2]*__expf(smm[2]-M2)+sms[3]*__expf(smm[3]-M2);
    int tgt=tok[base+r+1];
    ce[base+r]=M2+logf(S2)-row[tgt];
  }
}

__global__ __launch_bounds__(256) void k_final(const float* __restrict__ ce,
    const float* __restrict__ klh, const float* __restrict__ klc,
    const float* __restrict__ kldw, float* __restrict__ outp)
{
  int tid=threadIdx.x, lane=tid&63, wv=tid>>6;
  float s0=0,s1=0,s2=0;
  for(int i=tid;i<NSD;i+=256) s0+=ce[i];
  for(int i=tid;i<Hh;i+=256){ s1+=klh[i]; s2+=klc[i]; }
  s0=wave_reduce(s0); s1=wave_reduce(s1); s2=wave_reduce(s2);
  __shared__ float sm[3][4];
  if(lane==0){ sm[0][wv]=s0; sm[1][wv]=s1; sm[2][wv]=s2; }
  __syncthreads();
  if(tid==0){
    float ces=sm[0][0]+sm[0][1]+sm[0][2]+sm[0][3];
    float kh =sm[1][0]+sm[1][1]+sm[1][2]+sm[1][3];
    float kc =sm[2][0]+sm[2][1]+sm[2][2]+sm[2][3];
    float rec=ces/(float)NSD;
    outp[0]=rec+(kh+kc)*kldw[0];
    outp[1]=rec; outp[2]=kh; outp[3]=kc;
  }
}

extern "C" void kernel_launch(void* const* d_in, const int* in_sizes, int n_in,
                              void* d_out, int out_size, void* d_ws, size_t ws_size,
                              hipStream_t stream) {
  const int*   tok   =(const int*)  d_in[0];
  const int*   cond  =(const int*)  d_in[1];
  const float* eps_h =(const float*)d_in[2];
  const float* eps_c =(const float*)d_in[3];
  const float* kldw  =(const float*)d_in[4];
  const float* enc_embed=(const float*)d_in[5];
  const float* enc_cemb =(const float*)d_in[6];
  const float* enc_Wih  =(const float*)d_in[7];
  const float* enc_Whh  =(const float*)d_in[8];
  const float* enc_bih  =(const float*)d_in[9];
  const float* enc_bhh  =(const float*)d_in[10];
  const float* fc_mh_w=(const float*)d_in[11];
  const float* fc_mh_b=(const float*)d_in[12];
  const float* fc_lh_w=(const float*)d_in[13];
  const float* fc_lh_b=(const float*)d_in[14];
  const float* fc_mc_w=(const float*)d_in[15];
  const float* fc_mc_b=(const float*)d_in[16];
  const float* fc_lc_w=(const float*)d_in[17];
  const float* fc_lc_b=(const float*)d_in[18];
  const float* dec_embed=(const float*)d_in[19];
  const float* dec_cemb =(const float*)d_in[20];
  const float* dec_Wih  =(const float*)d_in[21];
  const float* dec_Whh  =(const float*)d_in[22];
  const float* dec_bih  =(const float*)d_in[23];
  const float* dec_bhh  =(const float*)d_in[24];
  const float* fc_h_w=(const float*)d_in[25];
  const float* fc_h_b=(const float*)d_in[26];
  const float* fc_c_w=(const float*)d_in[27];
  const float* fc_c_b=(const float*)d_in[28];
  const float* out_w=(const float*)d_in[29];
  const float* out_b=(const float*)d_in[30];

  float* ws=(float*)d_ws;
  size_t off=0;
  unsigned* estate=(unsigned*)(ws+off); off+=2*HCd;
  unsigned* dstate=(unsigned*)(ws+off); off+=4*HCd;
  float* cvec=ws+off; off+=G4;
  float* Weff=ws+off; off+=(size_t)G4*HCd;
  float* hT  =ws+off; off+=HCd;
  float* cT  =ws+off; off+=HCd;
  float* klh =ws+off; off+=Hh;
  float* klc =ws+off; off+=Hh;
  float* Hmat=ws+off; off+=(size_t)NSD*HCd;
  float* ce  =ws+off; off+=2048;
  size_t avail=ws_size/4;
  size_t xa_sz=(size_t)NSE*G4, xb_sz=(size_t)NSD*G4;
  size_t wb_sz=(size_t)VSZ*HCd/2;              // bf16 out_w, in float slots
  float* XA=ws+off;
  bool dual=(off+xa_sz+xb_sz)<=avail;
  float* XB=dual?(XA+xa_sz):XA;
  bool wbok=dual && (off+xa_sz+xb_sz+wb_sz)<=avail;
  unsigned* wB=(unsigned*)(XB+xb_sz);          // valid only if wbok
  size_t region=(avail>off)?(avail-off):0;
  int chunk=256;
  if(!dual){
    if((size_t)chunk*VSZ>region){ chunk=(int)(region/(size_t)VSZ); if(chunk<1)chunk=1; }
  }
  float* lbuf=XA;

  k_init3<<<1,256,0,stream>>>(estate,enc_cemb,cond);
  k_dconst<<<64,256,0,stream>>>(dec_Whh,fc_h_b,dec_cemb,cond,cvec);
  { dim3 g(G4/GBM, HCd/GBN);
    k_weff<<<g,256,0,stream>>>(dec_Whh,fc_h_w,Weff); }
  { dim3 g((NSE+GBM-1)/GBM, G4/GBN);           // Xenc (fp32)
    k_xgemm<<<g,256,0,stream>>>(enc_embed,enc_Wih,enc_bih,enc_bhh,tok,1,NSE,XA); }
  if(dual){
    dim3 g((NSD+TBM-1)/TBM, G4/TBN);           // Xdec (bf16 MFMA)
    k_xgemm_mfma<<<g,256,0,stream>>>(dec_embed,dec_Wih,dec_bih,dec_bhh,tok,NSD,XB);
  }
  if(wbok) k_cvtB<<<2048,256,0,stream>>>(out_w,wB);
  k_enc3<<<EB,ET,0,stream>>>(XA,enc_Whh,estate,hT,cT);
  k_head<<<Hh,256,0,stream>>>(hT,cT,fc_mh_w,fc_mh_b,fc_lh_w,fc_lh_b,
                              fc_mc_w,fc_mc_b,fc_lc_w,fc_lc_b,
                              eps_h,eps_c,dec_cemb,cond,dstate,klh,klc);
  if(!dual){
    dim3 g((NSD+TBM-1)/TBM, G4/TBN);           // Xdec overwrites Xenc (encoder done)
    k_xgemm_mfma<<<g,256,0,stream>>>(dec_embed,dec_Wih,dec_bih,dec_bhh,tok,NSD,XB);
  }
  k_dec0<<<256,256,0,stream>>>(XB,dec_Whh,dstate,dstate+2*HCd,Hmat);
  k_dec3<<<EB,ET,0,stream>>>(XB,Weff,cvec,fc_c_w,fc_c_b,dec_cemb,cond,dstate,Hmat);
  for(int base=0;base<NSD;base+=chunk){        // lbuf overlays XA — scans done
    int rows=NSD-base; if(rows>chunk) rows=chunk;
    dim3 g((rows+TBM-1)/TBM, VSZ/TBN);
    if(wbok) k_gemm2<<<g,256,0,stream>>>(Hmat+(size_t)base*HCd,(const ushort*)wB,out_b,lbuf,rows);
    else     k_gemm_mfma<<<g,256,0,stream>>>(Hmat+(size_t)base*HCd,out_w,out_b,lbuf,rows);
    k_ce<<<rows,256,0,stream>>>(lbuf,tok,base,ce);
  }
  k_final<<<1,256,0,stream>>>(ce,klh,klc,kldw,(float*)d_out);
}